// Round 6
// baseline (220.007 us; speedup 1.0000x reference)
//
#include <hip/hip_runtime.h>

#define N_NODES 50000
#define N_EDGES 800000
#define IN_C    128
#define HID_C   128
#define OUT_C   64
#define NBUCK   196                         // ceil(50000/256) buckets of 256 nodes
#define EPB     2048                        // edges per block in bucket kernels
#define EBLKS   ((N_EDGES + EPB - 1) / EPB) // 391
#define PACK_BLKS 192
#define MM1_BLKS  ((N_NODES + 63) / 64)     // 782

typedef unsigned short ushort_t;
typedef unsigned int   uint_t;
typedef unsigned char  uchar_t;
typedef __attribute__((ext_vector_type(8))) short bf16x8;
typedef __attribute__((ext_vector_type(4))) float f32x4;
typedef __attribute__((ext_vector_type(2))) float f32x2;

__device__ inline ushort_t f2bf(float f) {
    uint_t u = __float_as_uint(f);
    uint_t r = (u + 0x7fffu + ((u >> 16) & 1u)) >> 16;
    return (ushort_t)r;
}

// ---------------------------------------------------------------------------
// Weight pre-pack into B-fragment order for mfma_f32_16x16x32_bf16.
// ---------------------------------------------------------------------------
__device__ inline void pack_one(const float* W, ushort_t* Wp, int K, int N, int idx) {
    const int j  = idx & 7;
    const int L  = (idx >> 3) & 63;
    const int t  = idx >> 9;
    const int KT = K / 32;
    const int kt = t % KT;
    const int ct = t / KT;
    const int k  = kt * 32 + (L >> 4) * 8 + j;
    const int n  = ct * 16 + (L & 15);
    Wp[idx] = f2bf(W[k * N + n]);
}

// ---------------------------------------------------------------------------
// K0: pack weights (blocks 0..191) | bucket histogram (blocks 192..582).
// Disjoint data; no intra-launch dependencies.
// ---------------------------------------------------------------------------
__global__ __launch_bounds__(256) void k0_kernel(
    const float* __restrict__ W1l, const float* __restrict__ W1r,
    const float* __restrict__ W2l, const float* __restrict__ W2r,
    ushort_t* __restrict__ wpack,
    const int* __restrict__ dst, int* bcnt)
{
    __shared__ int lh[256];
    const int b = blockIdx.x;
    if (b < PACK_BLKS) {
        const int tid = b * 256 + threadIdx.x;
        if (tid < 16384)      pack_one(W1l, wpack,          IN_C,  HID_C, tid);
        else if (tid < 32768) pack_one(W1r, wpack + 16384,  IN_C,  HID_C, tid - 16384);
        else if (tid < 40960) pack_one(W2l, wpack + 32768,  HID_C, OUT_C, tid - 32768);
        else if (tid < 49152) pack_one(W2r, wpack + 40960,  HID_C, OUT_C, tid - 40960);
    } else {
        for (int i = threadIdx.x; i < NBUCK; i += 256) lh[i] = 0;
        __syncthreads();
        const int base = (b - PACK_BLKS) * EPB;
        for (int i = threadIdx.x; i < EPB; i += 256) {
            const int e = base + i;
            if (e < N_EDGES) atomicAdd(&lh[dst[e] >> 8], 1);
        }
        __syncthreads();
        for (int i = threadIdx.x; i < NBUCK; i += 256) {
            const int v = lh[i];
            if (v) atomicAdd(&bcnt[i], v);
        }
    }
}

// ---------------------------------------------------------------------------
// mm1 body: p1f = fp8(x @ W1l), t1b = bf16(x @ W1r).
// All inputs (wpack, x) produced before this launch.
// ---------------------------------------------------------------------------
__device__ inline void mm1_body(int bid, const float* __restrict__ x,
                                const ushort_t* __restrict__ wpack,
                                uchar_t* __restrict__ p1f, ushort_t* __restrict__ t1b)
{
    const int wave = threadIdx.x >> 6;
    const int lane = threadIdx.x & 63;
    const int quad = lane >> 4;
    const int m    = lane & 15;
    const int row0 = bid * 64 + wave * 16;
    const int arow = min(row0 + m, N_NODES - 1);

    const bf16x8* Bl = (const bf16x8*)(wpack);
    const bf16x8* Br = (const bf16x8*)(wpack + 16384);

    f32x4 accl[8], accr[8];
#pragma unroll
    for (int ct = 0; ct < 8; ++ct) { accl[ct] = (f32x4)(0.0f); accr[ct] = (f32x4)(0.0f); }

#pragma unroll
    for (int kt = 0; kt < 4; ++kt) {
        const float* xp = x + (size_t)arow * IN_C + kt * 32 + quad * 8;
        const float4 a0 = *(const float4*)(xp);
        const float4 a1 = *(const float4*)(xp + 4);
        bf16x8 af;
        af[0] = (short)f2bf(a0.x); af[1] = (short)f2bf(a0.y);
        af[2] = (short)f2bf(a0.z); af[3] = (short)f2bf(a0.w);
        af[4] = (short)f2bf(a1.x); af[5] = (short)f2bf(a1.y);
        af[6] = (short)f2bf(a1.z); af[7] = (short)f2bf(a1.w);
#pragma unroll
        for (int ct = 0; ct < 8; ++ct) {
            const bf16x8 bl = Bl[(ct * 4 + kt) * 64 + lane];
            const bf16x8 br = Br[(ct * 4 + kt) * 64 + lane];
            accl[ct] = __builtin_amdgcn_mfma_f32_16x16x32_bf16(af, bl, accl[ct], 0, 0, 0);
            accr[ct] = __builtin_amdgcn_mfma_f32_16x16x32_bf16(af, br, accr[ct], 0, 0, 0);
        }
    }

#pragma unroll
    for (int r = 0; r < 4; ++r) {
        const int orow = row0 + quad * 4 + r;
        if (orow < N_NODES) {
#pragma unroll
            for (int ct = 0; ct < 8; ++ct) {
                const int col = ct * 16 + m;
                const float v = accl[ct][r];
                const int pk = __builtin_amdgcn_cvt_pk_fp8_f32(v, v, 0, false);
                p1f[(size_t)orow * HID_C + col] = (uchar_t)(pk & 0xff);
                t1b[(size_t)orow * HID_C + col] = f2bf(accr[ct][r]);
            }
        }
    }
}

// ---------------------------------------------------------------------------
// K1: bucket scan (block 0) | mm1 (blocks 1..782). Both read only K0 outputs.
// ---------------------------------------------------------------------------
__global__ __launch_bounds__(256) void k1_kernel(
    const int* __restrict__ bcnt, int* __restrict__ ebase, int* __restrict__ gcur,
    const float* __restrict__ x, const ushort_t* __restrict__ wpack,
    uchar_t* __restrict__ p1f, ushort_t* __restrict__ t1b)
{
    __shared__ int s[256];
    if (blockIdx.x == 0) {
        const int t = threadIdx.x;
        const int v = (t < NBUCK) ? bcnt[t] : 0;
        s[t] = v;
        __syncthreads();
        for (int off = 1; off < 256; off <<= 1) {
            const int add = (t >= off) ? s[t - off] : 0;
            __syncthreads();
            s[t] += add;
            __syncthreads();
        }
        if (t < NBUCK) { const int ex = s[t] - v; ebase[t] = ex; gcur[t] = ex; }
        if (t == NBUCK - 1) ebase[NBUCK] = s[t];
    } else {
        mm1_body(blockIdx.x - 1, x, wpack, p1f, t1b);
    }
}

// ---------------------------------------------------------------------------
// Each block claims one contiguous run per bucket -> lines owned by one block.
// ---------------------------------------------------------------------------
__global__ __launch_bounds__(256) void bucket_scatter_kernel(
    const int* __restrict__ src, const int* __restrict__ dst,
    int* gcur, int2* __restrict__ ebuf)
{
    __shared__ int lh[256], gbase[256], lcur[256];
    const int t = threadIdx.x;
    lh[t] = 0;
    __syncthreads();
    const int base = blockIdx.x * EPB;
    int s8[8], d8[8], b8[8];
#pragma unroll
    for (int j = 0; j < 8; ++j) {
        const int e = base + t + j * 256;
        if (e < N_EDGES) {
            s8[j] = src[e]; d8[j] = dst[e]; b8[j] = d8[j] >> 8;
            atomicAdd(&lh[b8[j]], 1);
        } else b8[j] = -1;
    }
    __syncthreads();
    if (t < NBUCK) {
        const int run = lh[t];
        if (run > 0) gbase[t] = atomicAdd(&gcur[t], run);
        lcur[t] = 0;
    }
    __syncthreads();
#pragma unroll
    for (int j = 0; j < 8; ++j) {
        const int b = b8[j];
        if (b >= 0) {
            const int p = atomicAdd(&lcur[b], 1);
            ebuf[gbase[b] + p] = make_int2(s8[j], d8[j]);
        }
    }
}

// ---------------------------------------------------------------------------
// One block per bucket: local hist+scan over 256 nodes; cnt/row_ptr/csr.
// ---------------------------------------------------------------------------
__global__ __launch_bounds__(256) void bucket_fill_kernel(
    const int2* __restrict__ ebuf, const int* __restrict__ ebase,
    int* __restrict__ cnt, int* __restrict__ row_ptr, int* __restrict__ csr)
{
    __shared__ int lh[256], loff[256], lcur[256];
    const int b = blockIdx.x;
    const int t = threadIdx.x;
    const int e0 = ebase[b];
    const int nb = ebase[b + 1] - e0;
    lh[t] = 0;
    __syncthreads();
    for (int i = t; i < nb; i += 256) atomicAdd(&lh[ebuf[e0 + i].y & 255], 1);
    __syncthreads();
    const int v = lh[t];
    loff[t] = v;
    __syncthreads();
    for (int off = 1; off < 256; off <<= 1) {
        const int add = (t >= off) ? loff[t - off] : 0;
        __syncthreads();
        loff[t] += add;
        __syncthreads();
    }
    const int ex = loff[t] - v;
    const int node = b * 256 + t;
    if (node < N_NODES) { cnt[node] = v; row_ptr[node] = e0 + ex; }
    lcur[t] = ex;
    __syncthreads();
    for (int i = t; i < nb; i += 256) {
        const int2 pr = ebuf[e0 + i];
        const int p = atomicAdd(&lcur[pr.y & 255], 1);
        csr[e0 + p] = pr.x;
    }
}

// ---------------------------------------------------------------------------
// agg1: 4 nodes/block (wave per node), lane = channel pair, fp8 gathers.
// h = relu(mean(p1[src]) + b1 + t1), stored bf16.
// ---------------------------------------------------------------------------
__global__ __launch_bounds__(256) void agg1_kernel(
    const uchar_t* __restrict__ p1f, const ushort_t* __restrict__ t1b,
    const float* __restrict__ b1, const int* __restrict__ row_ptr,
    const int* __restrict__ cnt, const int* __restrict__ csr,
    ushort_t* __restrict__ hb)
{
    const int wave = threadIdx.x >> 6;
    const int lane = threadIdx.x & 63;
    const int node = blockIdx.x * 4 + wave;
    const int start = row_ptr[node];
    const int degi  = cnt[node];
    const ushort_t* p16 = (const ushort_t*)p1f;   // 2 fp8 per ushort; row stride 64

    float ax = 0.0f, ay = 0.0f;
    int e = 0;
    for (; e + 3 < degi; e += 4) {
        const int s0 = csr[start + e];
        const int s1 = csr[start + e + 1];
        const int s2 = csr[start + e + 2];
        const int s3 = csr[start + e + 3];
        const int v0 = p16[(size_t)s0 * 64 + lane];
        const int v1 = p16[(size_t)s1 * 64 + lane];
        const int v2 = p16[(size_t)s2 * 64 + lane];
        const int v3 = p16[(size_t)s3 * 64 + lane];
        const f32x2 f0 = __builtin_amdgcn_cvt_pk_f32_fp8(v0, false);
        const f32x2 f1 = __builtin_amdgcn_cvt_pk_f32_fp8(v1, false);
        const f32x2 f2 = __builtin_amdgcn_cvt_pk_f32_fp8(v2, false);
        const f32x2 f3 = __builtin_amdgcn_cvt_pk_f32_fp8(v3, false);
        ax += f0.x + f1.x + f2.x + f3.x;
        ay += f0.y + f1.y + f2.y + f3.y;
    }
    for (; e < degi; ++e) {
        const int v0 = p16[(size_t)csr[start + e] * 64 + lane];
        const f32x2 f0 = __builtin_amdgcn_cvt_pk_f32_fp8(v0, false);
        ax += f0.x; ay += f0.y;
    }

    const float inv = 1.0f / fmaxf((float)degi, 1.0f);
    const size_t i = (size_t)node * HID_C + lane * 2;
    const uint_t tv = *(const uint_t*)(t1b + i);
    const float t0 = __uint_as_float(tv << 16);
    const float t1 = __uint_as_float(tv & 0xffff0000u);
    const float2 bv = *(const float2*)(b1 + lane * 2);
    const float h0 = fmaxf(fmaf(ax, inv, bv.x + t0), 0.0f);
    const float h1 = fmaxf(fmaf(ay, inv, bv.y + t1), 0.0f);
    *(uint_t*)(hb + i) = (uint_t)f2bf(h0) | ((uint_t)f2bf(h1) << 16);
}

// ---------------------------------------------------------------------------
// Layer-2 MFMA dual matmul: p2b = bf16(h @ W2l), t2b = bf16(h @ W2r).
// ---------------------------------------------------------------------------
__global__ __launch_bounds__(256) void mm2_mfma(
    const ushort_t* __restrict__ hb,
    const ushort_t* __restrict__ wpack,
    ushort_t* __restrict__ p2b, ushort_t* __restrict__ t2b)
{
    const int wave = threadIdx.x >> 6;
    const int lane = threadIdx.x & 63;
    const int quad = lane >> 4;
    const int m    = lane & 15;
    const int row0 = blockIdx.x * 64 + wave * 16;
    const int arow = min(row0 + m, N_NODES - 1);

    const bf16x8* Bl = (const bf16x8*)(wpack + 32768);
    const bf16x8* Br = (const bf16x8*)(wpack + 40960);

    f32x4 accl[4], accr[4];
#pragma unroll
    for (int ct = 0; ct < 4; ++ct) { accl[ct] = (f32x4)(0.0f); accr[ct] = (f32x4)(0.0f); }

#pragma unroll
    for (int kt = 0; kt < 4; ++kt) {
        const bf16x8 af = *(const bf16x8*)(hb + (size_t)arow * HID_C + kt * 32 + quad * 8);
#pragma unroll
        for (int ct = 0; ct < 4; ++ct) {
            const bf16x8 bl = Bl[(ct * 4 + kt) * 64 + lane];
            const bf16x8 br = Br[(ct * 4 + kt) * 64 + lane];
            accl[ct] = __builtin_amdgcn_mfma_f32_16x16x32_bf16(af, bl, accl[ct], 0, 0, 0);
            accr[ct] = __builtin_amdgcn_mfma_f32_16x16x32_bf16(af, br, accr[ct], 0, 0, 0);
        }
    }

#pragma unroll
    for (int r = 0; r < 4; ++r) {
        const int orow = row0 + quad * 4 + r;
        if (orow < N_NODES) {
#pragma unroll
            for (int ct = 0; ct < 4; ++ct) {
                const int col = ct * 16 + m;
                p2b[(size_t)orow * OUT_C + col] = f2bf(accl[ct][r]);
                t2b[(size_t)orow * OUT_C + col] = f2bf(accr[ct][r]);
            }
        }
    }
}

// ---------------------------------------------------------------------------
// agg2: 4 nodes/block (wave per node), lane = channel, bf16 gathers.
// ---------------------------------------------------------------------------
__global__ __launch_bounds__(256) void agg2_kernel(
    const ushort_t* __restrict__ p2b, const ushort_t* __restrict__ t2b,
    const float* __restrict__ b2, const int* __restrict__ row_ptr,
    const int* __restrict__ cnt, const int* __restrict__ csr,
    float* __restrict__ out)
{
    const int wave = threadIdx.x >> 6;
    const int lane = threadIdx.x & 63;
    const int node = blockIdx.x * 4 + wave;
    const int start = row_ptr[node];
    const int degi  = cnt[node];

    float acc = 0.0f;
    int e = 0;
    for (; e + 3 < degi; e += 4) {
        const int s0 = csr[start + e];
        const int s1 = csr[start + e + 1];
        const int s2 = csr[start + e + 2];
        const int s3 = csr[start + e + 3];
        const uint_t u0 = p2b[(size_t)s0 * OUT_C + lane];
        const uint_t u1 = p2b[(size_t)s1 * OUT_C + lane];
        const uint_t u2 = p2b[(size_t)s2 * OUT_C + lane];
        const uint_t u3 = p2b[(size_t)s3 * OUT_C + lane];
        acc += __uint_as_float(u0 << 16) + __uint_as_float(u1 << 16)
             + __uint_as_float(u2 << 16) + __uint_as_float(u3 << 16);
    }
    for (; e < degi; ++e) {
        const uint_t u0 = p2b[(size_t)csr[start + e] * OUT_C + lane];
        acc += __uint_as_float(u0 << 16);
    }

    const float inv = 1.0f / fmaxf((float)degi, 1.0f);
    const size_t i = (size_t)node * OUT_C + lane;
    const float t2 = __uint_as_float(((uint_t)t2b[i]) << 16);
    out[i] = fmaf(acc, inv, b2[lane] + t2);
}

extern "C" void kernel_launch(void* const* d_in, const int* in_sizes, int n_in,
                              void* d_out, int out_size, void* d_ws, size_t ws_size,
                              hipStream_t stream)
{
    const float* x   = (const float*)d_in[0];
    const int*   ei  = (const int*)d_in[1];
    const float* W1l = (const float*)d_in[2];
    const float* b1  = (const float*)d_in[3];
    const float* W1r = (const float*)d_in[4];
    const float* W2l = (const float*)d_in[5];
    const float* b2  = (const float*)d_in[6];
    const float* W2r = (const float*)d_in[7];
    float* out = (float*)d_out;

    const int* src = ei;
    const int* dst = ei + N_EDGES;

    const size_t NH = (size_t)N_NODES * HID_C;   // 6.4M
    const size_t NO = (size_t)N_NODES * OUT_C;   // 3.2M

    // Workspace layout. int2 first (8B align), then ushort, int, bytes.
    char* ws = (char*)d_ws;
    int2*     ebuf  = (int2*)ws;                       ws += N_EDGES * sizeof(int2);
    ushort_t* t1b   = (ushort_t*)ws;                   ws += NH * sizeof(ushort_t);
    ushort_t* hb    = (ushort_t*)ws;                   ws += NH * sizeof(ushort_t);
    ushort_t* t2b   = (ushort_t*)ws;                   ws += NO * sizeof(ushort_t);
    ushort_t* p2b   = (ushort_t*)ws;                   ws += NO * sizeof(ushort_t);
    ushort_t* wpack = (ushort_t*)ws;                   ws += 49152 * sizeof(ushort_t);
    int* cnt     = (int*)ws;                           ws += N_NODES * sizeof(int);
    int* row_ptr = (int*)ws;                           ws += N_NODES * sizeof(int);
    int* csr     = (int*)ws;                           ws += N_EDGES * sizeof(int);
    int* bcnt    = (int*)ws;                           ws += NBUCK * sizeof(int);
    int* ebase   = (int*)ws;                           ws += (NBUCK + 1) * sizeof(int);
    int* gcur    = (int*)ws;                           ws += NBUCK * sizeof(int);
    uchar_t* p1f = (uchar_t*)ws;                       ws += NH * sizeof(uchar_t);

    const size_t need = (size_t)(ws - (char*)d_ws);
    if (ws_size < need) return;

    hipMemsetAsync(bcnt, 0, NBUCK * sizeof(int), stream);

    // K0: pack | count        (both input-only)
    k0_kernel<<<PACK_BLKS + EBLKS, 256, 0, stream>>>(
        W1l, W1r, W2l, W2r, wpack, dst, bcnt);
    // K1: scan | mm1-all      (both read only K0 outputs / inputs)
    k1_kernel<<<1 + MM1_BLKS, 256, 0, stream>>>(bcnt, ebase, gcur, x, wpack, p1f, t1b);

    bucket_scatter_kernel<<<EBLKS, 256, 0, stream>>>(src, dst, gcur, ebuf);
    bucket_fill_kernel<<<NBUCK, 256, 0, stream>>>(ebuf, ebase, cnt, row_ptr, csr);

    agg1_kernel<<<N_NODES / 4, 256, 0, stream>>>(p1f, t1b, b1, row_ptr, cnt, csr, hb);
    mm2_mfma<<<MM1_BLKS, 256, 0, stream>>>(hb, wpack, p2b, t2b);
    agg2_kernel<<<N_NODES / 4, 256, 0, stream>>>(p2b, t2b, b2, row_ptr, cnt, csr, out);
}

// Round 7
// 181.481 us; speedup vs baseline: 1.2123x; 1.2123x over previous
//
#include <hip/hip_runtime.h>

#define N_NODES 50000
#define N_EDGES 800000
#define IN_C    128
#define HID_C   128
#define OUT_C   64
#define NBUCK   196                         // ceil(50000/256) buckets of 256 nodes
#define BCAP    6144                        // fixed slots/bucket (mean 4082, sigma 64 -> 32 sigma)
#define EPB     2048                        // edges per scatter block
#define EBLKS   ((N_EDGES + EPB - 1) / EPB) // 391
#define PACK_BLKS 192
#define MM1_BLKS  ((N_NODES + 63) / 64)     // 782

typedef unsigned short ushort_t;
typedef unsigned int   uint_t;
typedef unsigned char  uchar_t;
typedef __attribute__((ext_vector_type(8))) short bf16x8;
typedef __attribute__((ext_vector_type(4))) float f32x4;
typedef __attribute__((ext_vector_type(2))) float f32x2;

__device__ inline ushort_t f2bf(float f) {
    uint_t u = __float_as_uint(f);
    uint_t r = (u + 0x7fffu + ((u >> 16) & 1u)) >> 16;
    return (ushort_t)r;
}
__device__ inline float bflo(uint_t v) { return __uint_as_float(v << 16); }
__device__ inline float bfhi(uint_t v) { return __uint_as_float(v & 0xffff0000u); }

// ---------------------------------------------------------------------------
// Weight pre-pack into B-fragment order for mfma_f32_16x16x32_bf16.
// ---------------------------------------------------------------------------
__device__ inline void pack_one(const float* W, ushort_t* Wp, int K, int N, int idx) {
    const int j  = idx & 7;
    const int L  = (idx >> 3) & 63;
    const int t  = idx >> 9;
    const int KT = K / 32;
    const int kt = t % KT;
    const int ct = t / KT;
    const int k  = kt * 32 + (L >> 4) * 8 + j;
    const int n  = ct * 16 + (L & 15);
    Wp[idx] = f2bf(W[k * N + n]);
}

// ---------------------------------------------------------------------------
// K0: pack weights (blocks 0..191) | zero bucket cursors (block 192).
// All branches read only kernel inputs; disjoint outputs.
// ---------------------------------------------------------------------------
__global__ __launch_bounds__(256) void k0_kernel(
    const float* __restrict__ W1l, const float* __restrict__ W1r,
    const float* __restrict__ W2l, const float* __restrict__ W2r,
    ushort_t* __restrict__ wpack, int* __restrict__ gcur)
{
    const int b = blockIdx.x;
    if (b < PACK_BLKS) {
        const int tid = b * 256 + threadIdx.x;
        if (tid < 16384)      pack_one(W1l, wpack,          IN_C,  HID_C, tid);
        else if (tid < 32768) pack_one(W1r, wpack + 16384,  IN_C,  HID_C, tid - 16384);
        else if (tid < 40960) pack_one(W2l, wpack + 32768,  HID_C, OUT_C, tid - 32768);
        else if (tid < 49152) pack_one(W2r, wpack + 40960,  HID_C, OUT_C, tid - 40960);
    } else {
        if (threadIdx.x < NBUCK) gcur[threadIdx.x] = 0;
    }
}

// ---------------------------------------------------------------------------
// mm1 body: p1f = fp8(x @ W1l), t1b = bf16(x @ W1r). wpack from K0.
// ---------------------------------------------------------------------------
__device__ inline void mm1_body(int bid, const float* __restrict__ x,
                                const ushort_t* __restrict__ wpack,
                                uchar_t* __restrict__ p1f, ushort_t* __restrict__ t1b)
{
    const int wave = threadIdx.x >> 6;
    const int lane = threadIdx.x & 63;
    const int quad = lane >> 4;
    const int m    = lane & 15;
    const int row0 = bid * 64 + wave * 16;
    const int arow = min(row0 + m, N_NODES - 1);

    const bf16x8* Bl = (const bf16x8*)(wpack);
    const bf16x8* Br = (const bf16x8*)(wpack + 16384);

    f32x4 accl[8], accr[8];
#pragma unroll
    for (int ct = 0; ct < 8; ++ct) { accl[ct] = (f32x4)(0.0f); accr[ct] = (f32x4)(0.0f); }

#pragma unroll
    for (int kt = 0; kt < 4; ++kt) {
        const float* xp = x + (size_t)arow * IN_C + kt * 32 + quad * 8;
        const float4 a0 = *(const float4*)(xp);
        const float4 a1 = *(const float4*)(xp + 4);
        bf16x8 af;
        af[0] = (short)f2bf(a0.x); af[1] = (short)f2bf(a0.y);
        af[2] = (short)f2bf(a0.z); af[3] = (short)f2bf(a0.w);
        af[4] = (short)f2bf(a1.x); af[5] = (short)f2bf(a1.y);
        af[6] = (short)f2bf(a1.z); af[7] = (short)f2bf(a1.w);
#pragma unroll
        for (int ct = 0; ct < 8; ++ct) {
            const bf16x8 bl = Bl[(ct * 4 + kt) * 64 + lane];
            const bf16x8 br = Br[(ct * 4 + kt) * 64 + lane];
            accl[ct] = __builtin_amdgcn_mfma_f32_16x16x32_bf16(af, bl, accl[ct], 0, 0, 0);
            accr[ct] = __builtin_amdgcn_mfma_f32_16x16x32_bf16(af, br, accr[ct], 0, 0, 0);
        }
    }

#pragma unroll
    for (int r = 0; r < 4; ++r) {
        const int orow = row0 + quad * 4 + r;
        if (orow < N_NODES) {
#pragma unroll
            for (int ct = 0; ct < 8; ++ct) {
                const int col = ct * 16 + m;
                const float v = accl[ct][r];
                const int pk = __builtin_amdgcn_cvt_pk_fp8_f32(v, v, 0, false);
                p1f[(size_t)orow * HID_C + col] = (uchar_t)(pk & 0xff);
                t1b[(size_t)orow * HID_C + col] = f2bf(accr[ct][r]);
            }
        }
    }
}

// ---------------------------------------------------------------------------
// K1: mm1 (blocks 0..781) | bucket scatter (blocks 782..1172).
// Both read only K0 outputs / kernel inputs; disjoint writes.
// Scatter: per-block LDS hist -> claim contiguous run per bucket via gcur ->
// write packed (src<<8 | dst&255) into the bucket's fixed BCAP range.
// ---------------------------------------------------------------------------
__global__ __launch_bounds__(256) void k1_kernel(
    const float* __restrict__ x, const ushort_t* __restrict__ wpack,
    uchar_t* __restrict__ p1f, ushort_t* __restrict__ t1b,
    const int* __restrict__ src, const int* __restrict__ dst,
    int* gcur, int* __restrict__ ebuf)
{
    __shared__ int lh[256], gbase[256], lcur[256];
    const int b = blockIdx.x;
    if (b < MM1_BLKS) {
        mm1_body(b, x, wpack, p1f, t1b);
        return;
    }
    const int blk = b - MM1_BLKS;
    const int t = threadIdx.x;
    lh[t] = 0;
    __syncthreads();
    const int base = blk * EPB;
    int v8[8], b8[8];
#pragma unroll
    for (int j = 0; j < 8; ++j) {
        const int e = base + t + j * 256;
        if (e < N_EDGES) {
            const int s = src[e], d = dst[e];
            b8[j] = d >> 8;
            v8[j] = (s << 8) | (d & 255);
            atomicAdd(&lh[b8[j]], 1);
        } else b8[j] = -1;
    }
    __syncthreads();
    if (t < NBUCK) {
        const int run = lh[t];
        gbase[t] = (run > 0) ? atomicAdd(&gcur[t], run) : 0;
        lcur[t] = 0;
    }
    __syncthreads();
#pragma unroll
    for (int j = 0; j < 8; ++j) {
        const int bk = b8[j];
        if (bk >= 0) {
            const int p = atomicAdd(&lcur[bk], 1);
            ebuf[bk * BCAP + gbase[bk] + p] = v8[j];
        }
    }
}

// ---------------------------------------------------------------------------
// fill: one block per bucket. Local 256-node hist+scan; writes cnt, row_ptr,
// and csr (= src indices sorted by node) in the bucket's exclusive range.
// ---------------------------------------------------------------------------
__global__ __launch_bounds__(256) void fill_kernel(
    const int* __restrict__ ebuf, const int* __restrict__ gcur,
    int* __restrict__ cnt, int* __restrict__ row_ptr, int* __restrict__ csr)
{
    __shared__ int lh[256], loff[256], lcur[256];
    const int b = blockIdx.x;
    const int t = threadIdx.x;
    const int e0 = b * BCAP;
    const int nb = gcur[b];
    lh[t] = 0;
    __syncthreads();
    for (int i = t; i < nb; i += 256) atomicAdd(&lh[ebuf[e0 + i] & 255], 1);
    __syncthreads();
    const int v = lh[t];
    loff[t] = v;
    __syncthreads();
    for (int off = 1; off < 256; off <<= 1) {
        const int add = (t >= off) ? loff[t - off] : 0;
        __syncthreads();
        loff[t] += add;
        __syncthreads();
    }
    const int ex = loff[t] - v;
    const int node = b * 256 + t;
    if (node < N_NODES) { cnt[node] = v; row_ptr[node] = e0 + ex; }
    lcur[t] = ex;
    __syncthreads();
    for (int i = t; i < nb; i += 256) {
        const int pr = ebuf[e0 + i];
        const int p = atomicAdd(&lcur[pr & 255], 1);
        csr[e0 + p] = pr >> 8;
    }
}

// ---------------------------------------------------------------------------
// agg1: 8 nodes/block, 32 lanes/node (half-wave), 4 fp8 channels per lane.
// One 4B load per lane fetches a full 128B row per half-wave per edge.
// h = relu(mean(p1[src]) + b1 + t1), stored bf16.
// ---------------------------------------------------------------------------
__global__ __launch_bounds__(256) void agg1_kernel(
    const uchar_t* __restrict__ p1f, const ushort_t* __restrict__ t1b,
    const float* __restrict__ b1, const int* __restrict__ row_ptr,
    const int* __restrict__ cnt, const int* __restrict__ csr,
    ushort_t* __restrict__ hb)
{
    const int wave = threadIdx.x >> 6;
    const int half = (threadIdx.x >> 5) & 1;
    const int c4   = threadIdx.x & 31;          // channel group: 4*c4 .. 4*c4+3
    const int node = blockIdx.x * 8 + wave * 2 + half;
    const int start = row_ptr[node];
    const int degi  = cnt[node];
    const uint_t* p1u = (const uint_t*)p1f;     // row stride 32 uints

    float a0 = 0.0f, a1 = 0.0f, a2 = 0.0f, a3 = 0.0f;
    int e = 0;
    for (; e + 3 < degi; e += 4) {
        const int s0 = csr[start + e];
        const int s1 = csr[start + e + 1];
        const int s2 = csr[start + e + 2];
        const int s3 = csr[start + e + 3];
        const uint_t v0 = p1u[(size_t)s0 * 32 + c4];
        const uint_t v1 = p1u[(size_t)s1 * 32 + c4];
        const uint_t v2 = p1u[(size_t)s2 * 32 + c4];
        const uint_t v3 = p1u[(size_t)s3 * 32 + c4];
        const f32x2 l0 = __builtin_amdgcn_cvt_pk_f32_fp8((int)v0, false);
        const f32x2 h0 = __builtin_amdgcn_cvt_pk_f32_fp8((int)v0, true);
        const f32x2 l1 = __builtin_amdgcn_cvt_pk_f32_fp8((int)v1, false);
        const f32x2 h1 = __builtin_amdgcn_cvt_pk_f32_fp8((int)v1, true);
        const f32x2 l2 = __builtin_amdgcn_cvt_pk_f32_fp8((int)v2, false);
        const f32x2 h2 = __builtin_amdgcn_cvt_pk_f32_fp8((int)v2, true);
        const f32x2 l3 = __builtin_amdgcn_cvt_pk_f32_fp8((int)v3, false);
        const f32x2 h3 = __builtin_amdgcn_cvt_pk_f32_fp8((int)v3, true);
        a0 += l0.x + l1.x + l2.x + l3.x;
        a1 += l0.y + l1.y + l2.y + l3.y;
        a2 += h0.x + h1.x + h2.x + h3.x;
        a3 += h0.y + h1.y + h2.y + h3.y;
    }
    for (; e < degi; ++e) {
        const uint_t v0 = p1u[(size_t)csr[start + e] * 32 + c4];
        const f32x2 l0 = __builtin_amdgcn_cvt_pk_f32_fp8((int)v0, false);
        const f32x2 h0 = __builtin_amdgcn_cvt_pk_f32_fp8((int)v0, true);
        a0 += l0.x; a1 += l0.y; a2 += h0.x; a3 += h0.y;
    }

    const float inv = 1.0f / fmaxf((float)degi, 1.0f);
    const size_t i = (size_t)node * HID_C + c4 * 4;
    const uint2 tv = *(const uint2*)(t1b + i);
    const float4 bv = *(const float4*)(b1 + c4 * 4);
    const float r0 = fmaxf(fmaf(a0, inv, bv.x + bflo(tv.x)), 0.0f);
    const float r1 = fmaxf(fmaf(a1, inv, bv.y + bfhi(tv.x)), 0.0f);
    const float r2 = fmaxf(fmaf(a2, inv, bv.z + bflo(tv.y)), 0.0f);
    const float r3 = fmaxf(fmaf(a3, inv, bv.w + bfhi(tv.y)), 0.0f);
    uint2 o;
    o.x = (uint_t)f2bf(r0) | ((uint_t)f2bf(r1) << 16);
    o.y = (uint_t)f2bf(r2) | ((uint_t)f2bf(r3) << 16);
    *(uint2*)(hb + i) = o;
}

// ---------------------------------------------------------------------------
// Layer-2 MFMA dual matmul: p2b = bf16(h @ W2l), t2b = bf16(h @ W2r).
// ---------------------------------------------------------------------------
__global__ __launch_bounds__(256) void mm2_mfma(
    const ushort_t* __restrict__ hb,
    const ushort_t* __restrict__ wpack,
    ushort_t* __restrict__ p2b, ushort_t* __restrict__ t2b)
{
    const int wave = threadIdx.x >> 6;
    const int lane = threadIdx.x & 63;
    const int quad = lane >> 4;
    const int m    = lane & 15;
    const int row0 = blockIdx.x * 64 + wave * 16;
    const int arow = min(row0 + m, N_NODES - 1);

    const bf16x8* Bl = (const bf16x8*)(wpack + 32768);
    const bf16x8* Br = (const bf16x8*)(wpack + 40960);

    f32x4 accl[4], accr[4];
#pragma unroll
    for (int ct = 0; ct < 4; ++ct) { accl[ct] = (f32x4)(0.0f); accr[ct] = (f32x4)(0.0f); }

#pragma unroll
    for (int kt = 0; kt < 4; ++kt) {
        const bf16x8 af = *(const bf16x8*)(hb + (size_t)arow * HID_C + kt * 32 + quad * 8);
#pragma unroll
        for (int ct = 0; ct < 4; ++ct) {
            const bf16x8 bl = Bl[(ct * 4 + kt) * 64 + lane];
            const bf16x8 br = Br[(ct * 4 + kt) * 64 + lane];
            accl[ct] = __builtin_amdgcn_mfma_f32_16x16x32_bf16(af, bl, accl[ct], 0, 0, 0);
            accr[ct] = __builtin_amdgcn_mfma_f32_16x16x32_bf16(af, br, accr[ct], 0, 0, 0);
        }
    }

#pragma unroll
    for (int r = 0; r < 4; ++r) {
        const int orow = row0 + quad * 4 + r;
        if (orow < N_NODES) {
#pragma unroll
            for (int ct = 0; ct < 4; ++ct) {
                const int col = ct * 16 + m;
                p2b[(size_t)orow * OUT_C + col] = f2bf(accl[ct][r]);
                t2b[(size_t)orow * OUT_C + col] = f2bf(accr[ct][r]);
            }
        }
    }
}

// ---------------------------------------------------------------------------
// agg2: 8 nodes/block, 32 lanes/node, 2 bf16 channels per lane (4B loads).
// out = mean(p2[src]) + b2 + t2.
// ---------------------------------------------------------------------------
__global__ __launch_bounds__(256) void agg2_kernel(
    const ushort_t* __restrict__ p2b, const ushort_t* __restrict__ t2b,
    const float* __restrict__ b2, const int* __restrict__ row_ptr,
    const int* __restrict__ cnt, const int* __restrict__ csr,
    float* __restrict__ out)
{
    const int wave = threadIdx.x >> 6;
    const int half = (threadIdx.x >> 5) & 1;
    const int c2   = threadIdx.x & 31;          // channels 2*c2, 2*c2+1
    const int node = blockIdx.x * 8 + wave * 2 + half;
    const int start = row_ptr[node];
    const int degi  = cnt[node];
    const uint_t* p2u = (const uint_t*)p2b;     // row stride 32 uints

    float a0 = 0.0f, a1 = 0.0f;
    int e = 0;
    for (; e + 3 < degi; e += 4) {
        const int s0 = csr[start + e];
        const int s1 = csr[start + e + 1];
        const int s2 = csr[start + e + 2];
        const int s3 = csr[start + e + 3];
        const uint_t v0 = p2u[(size_t)s0 * 32 + c2];
        const uint_t v1 = p2u[(size_t)s1 * 32 + c2];
        const uint_t v2 = p2u[(size_t)s2 * 32 + c2];
        const uint_t v3 = p2u[(size_t)s3 * 32 + c2];
        a0 += bflo(v0) + bflo(v1) + bflo(v2) + bflo(v3);
        a1 += bfhi(v0) + bfhi(v1) + bfhi(v2) + bfhi(v3);
    }
    for (; e < degi; ++e) {
        const uint_t v0 = p2u[(size_t)csr[start + e] * 32 + c2];
        a0 += bflo(v0); a1 += bfhi(v0);
    }

    const float inv = 1.0f / fmaxf((float)degi, 1.0f);
    const size_t i = (size_t)node * OUT_C + c2 * 2;
    const uint_t tv = *(const uint_t*)(t2b + i);
    const float2 bv = *(const float2*)(b2 + c2 * 2);
    float2 o;
    o.x = fmaf(a0, inv, bv.x + bflo(tv));
    o.y = fmaf(a1, inv, bv.y + bfhi(tv));
    *(float2*)(out + i) = o;
}

extern "C" void kernel_launch(void* const* d_in, const int* in_sizes, int n_in,
                              void* d_out, int out_size, void* d_ws, size_t ws_size,
                              hipStream_t stream)
{
    const float* x   = (const float*)d_in[0];
    const int*   ei  = (const int*)d_in[1];
    const float* W1l = (const float*)d_in[2];
    const float* b1  = (const float*)d_in[3];
    const float* W1r = (const float*)d_in[4];
    const float* W2l = (const float*)d_in[5];
    const float* b2  = (const float*)d_in[6];
    const float* W2r = (const float*)d_in[7];
    float* out = (float*)d_out;

    const int* src = ei;
    const int* dst = ei + N_EDGES;

    const size_t NH = (size_t)N_NODES * HID_C;   // 6.4M
    const size_t NO = (size_t)N_NODES * OUT_C;   // 3.2M
    const size_t EB = (size_t)NBUCK * BCAP;      // 1.204M slots

    // Workspace layout (8B-aligned first).
    char* ws = (char*)d_ws;
    ushort_t* t1b   = (ushort_t*)ws;                   ws += NH * sizeof(ushort_t);
    ushort_t* hb    = (ushort_t*)ws;                   ws += NH * sizeof(ushort_t);
    ushort_t* t2b   = (ushort_t*)ws;                   ws += NO * sizeof(ushort_t);
    ushort_t* p2b   = (ushort_t*)ws;                   ws += NO * sizeof(ushort_t);
    ushort_t* wpack = (ushort_t*)ws;                   ws += 49152 * sizeof(ushort_t);
    int* ebuf    = (int*)ws;                           ws += EB * sizeof(int);
    int* csr     = (int*)ws;                           ws += EB * sizeof(int);
    int* cnt     = (int*)ws;                           ws += N_NODES * sizeof(int);
    int* row_ptr = (int*)ws;                           ws += N_NODES * sizeof(int);
    int* gcur    = (int*)ws;                           ws += NBUCK * sizeof(int);
    uchar_t* p1f = (uchar_t*)ws;                       ws += NH * sizeof(uchar_t);

    const size_t need = (size_t)(ws - (char*)d_ws);
    if (ws_size < need) return;

    // K0: pack weights | zero bucket cursors        (input-only)
    k0_kernel<<<PACK_BLKS + 1, 256, 0, stream>>>(W1l, W1r, W2l, W2r, wpack, gcur);
    // K1: mm1 | bucket scatter                      (reads only K0 outputs/inputs)
    k1_kernel<<<MM1_BLKS + EBLKS, 256, 0, stream>>>(
        x, wpack, p1f, t1b, src, dst, gcur, ebuf);
    // CSR finalize (per-bucket exclusive ranges)
    fill_kernel<<<NBUCK, 256, 0, stream>>>(ebuf, gcur, cnt, row_ptr, csr);

    agg1_kernel<<<N_NODES / 8, 256, 0, stream>>>(p1f, t1b, b1, row_ptr, cnt, csr, hb);
    mm2_mfma<<<MM1_BLKS, 256, 0, stream>>>(hb, wpack, p2b, t2b);
    agg2_kernel<<<N_NODES / 8, 256, 0, stream>>>(p2b, t2b, b2, row_ptr, cnt, csr, out);
}

// Round 8
// 177.197 us; speedup vs baseline: 1.2416x; 1.0242x over previous
//
#include <hip/hip_runtime.h>

#define N_NODES 50000
#define N_EDGES 800000
#define IN_C    128
#define HID_C   128
#define OUT_C   64
#define NBUCK   196                         // ceil(50000/256) buckets of 256 nodes
#define BCAP    6144                        // fixed slots/bucket (mean 4082 -> 32 sigma headroom)
#define EPB     2048                        // edges per scatter block
#define EBLKS   ((N_EDGES + EPB - 1) / EPB) // 391
#define PACK_BLKS 192
#define MM1_BLKS  ((N_NODES + 63) / 64)     // 782
#define HS_STRIDE 136                       // 128 ushorts + 8 pad -> 272B rows, 2-way-free banks

typedef unsigned short ushort_t;
typedef unsigned int   uint_t;
typedef unsigned char  uchar_t;
typedef __attribute__((ext_vector_type(8))) short bf16x8;
typedef __attribute__((ext_vector_type(4))) float f32x4;
typedef __attribute__((ext_vector_type(2))) float f32x2;

__device__ inline ushort_t f2bf(float f) {
    uint_t u = __float_as_uint(f);
    uint_t r = (u + 0x7fffu + ((u >> 16) & 1u)) >> 16;
    return (ushort_t)r;
}
__device__ inline float bflo(uint_t v) { return __uint_as_float(v << 16); }
__device__ inline float bfhi(uint_t v) { return __uint_as_float(v & 0xffff0000u); }

// ---------------------------------------------------------------------------
// Weight pre-pack into B-fragment order for mfma_f32_16x16x32_bf16.
// ---------------------------------------------------------------------------
__device__ inline void pack_one(const float* W, ushort_t* Wp, int K, int N, int idx) {
    const int j  = idx & 7;
    const int L  = (idx >> 3) & 63;
    const int t  = idx >> 9;
    const int KT = K / 32;
    const int kt = t % KT;
    const int ct = t / KT;
    const int k  = kt * 32 + (L >> 4) * 8 + j;
    const int n  = ct * 16 + (L & 15);
    Wp[idx] = f2bf(W[k * N + n]);
}

// ---------------------------------------------------------------------------
// K0: pack weights (blocks 0..191) | zero bucket cursors (block 192).
// ---------------------------------------------------------------------------
__global__ __launch_bounds__(256) void k0_kernel(
    const float* __restrict__ W1l, const float* __restrict__ W1r,
    const float* __restrict__ W2l, const float* __restrict__ W2r,
    ushort_t* __restrict__ wpack, int* __restrict__ gcur)
{
    const int b = blockIdx.x;
    if (b < PACK_BLKS) {
        const int tid = b * 256 + threadIdx.x;
        if (tid < 16384)      pack_one(W1l, wpack,          IN_C,  HID_C, tid);
        else if (tid < 32768) pack_one(W1r, wpack + 16384,  IN_C,  HID_C, tid - 16384);
        else if (tid < 40960) pack_one(W2l, wpack + 32768,  HID_C, OUT_C, tid - 32768);
        else if (tid < 49152) pack_one(W2r, wpack + 40960,  HID_C, OUT_C, tid - 40960);
    } else {
        if (threadIdx.x < NBUCK) gcur[threadIdx.x] = 0;
    }
}

// ---------------------------------------------------------------------------
// mm1 body: p1f = fp8(x @ W1l), t1b = bf16(x @ W1r). wpack from K0.
// ---------------------------------------------------------------------------
__device__ inline void mm1_body(int bid, const float* __restrict__ x,
                                const ushort_t* __restrict__ wpack,
                                uchar_t* __restrict__ p1f, ushort_t* __restrict__ t1b)
{
    const int wave = threadIdx.x >> 6;
    const int lane = threadIdx.x & 63;
    const int quad = lane >> 4;
    const int m    = lane & 15;
    const int row0 = bid * 64 + wave * 16;
    const int arow = min(row0 + m, N_NODES - 1);

    const bf16x8* Bl = (const bf16x8*)(wpack);
    const bf16x8* Br = (const bf16x8*)(wpack + 16384);

    f32x4 accl[8], accr[8];
#pragma unroll
    for (int ct = 0; ct < 8; ++ct) { accl[ct] = (f32x4)(0.0f); accr[ct] = (f32x4)(0.0f); }

#pragma unroll
    for (int kt = 0; kt < 4; ++kt) {
        const float* xp = x + (size_t)arow * IN_C + kt * 32 + quad * 8;
        const float4 a0 = *(const float4*)(xp);
        const float4 a1 = *(const float4*)(xp + 4);
        bf16x8 af;
        af[0] = (short)f2bf(a0.x); af[1] = (short)f2bf(a0.y);
        af[2] = (short)f2bf(a0.z); af[3] = (short)f2bf(a0.w);
        af[4] = (short)f2bf(a1.x); af[5] = (short)f2bf(a1.y);
        af[6] = (short)f2bf(a1.z); af[7] = (short)f2bf(a1.w);
#pragma unroll
        for (int ct = 0; ct < 8; ++ct) {
            const bf16x8 bl = Bl[(ct * 4 + kt) * 64 + lane];
            const bf16x8 br = Br[(ct * 4 + kt) * 64 + lane];
            accl[ct] = __builtin_amdgcn_mfma_f32_16x16x32_bf16(af, bl, accl[ct], 0, 0, 0);
            accr[ct] = __builtin_amdgcn_mfma_f32_16x16x32_bf16(af, br, accr[ct], 0, 0, 0);
        }
    }

#pragma unroll
    for (int r = 0; r < 4; ++r) {
        const int orow = row0 + quad * 4 + r;
        if (orow < N_NODES) {
#pragma unroll
            for (int ct = 0; ct < 8; ++ct) {
                const int col = ct * 16 + m;
                const float v = accl[ct][r];
                const int pk = __builtin_amdgcn_cvt_pk_fp8_f32(v, v, 0, false);
                p1f[(size_t)orow * HID_C + col] = (uchar_t)(pk & 0xff);
                t1b[(size_t)orow * HID_C + col] = f2bf(accr[ct][r]);
            }
        }
    }
}

// ---------------------------------------------------------------------------
// K1: mm1 (blocks 0..781) | bucket scatter (blocks 782..1172).
// Scatter: LDS hist -> claim run per bucket via gcur -> packed (src<<8|dst&255).
// ---------------------------------------------------------------------------
__global__ __launch_bounds__(256) void k1_kernel(
    const float* __restrict__ x, const ushort_t* __restrict__ wpack,
    uchar_t* __restrict__ p1f, ushort_t* __restrict__ t1b,
    const int* __restrict__ src, const int* __restrict__ dst,
    int* gcur, int* __restrict__ ebuf)
{
    __shared__ int lh[256], gbase[256], lcur[256];
    const int b = blockIdx.x;
    if (b < MM1_BLKS) {
        mm1_body(b, x, wpack, p1f, t1b);
        return;
    }
    const int blk = b - MM1_BLKS;
    const int t = threadIdx.x;
    lh[t] = 0;
    __syncthreads();
    const int base = blk * EPB;
    int v8[8], b8[8];
#pragma unroll
    for (int j = 0; j < 8; ++j) {
        const int e = base + t + j * 256;
        if (e < N_EDGES) {
            const int s = src[e], d = dst[e];
            b8[j] = d >> 8;
            v8[j] = (s << 8) | (d & 255);
            atomicAdd(&lh[b8[j]], 1);
        } else b8[j] = -1;
    }
    __syncthreads();
    if (t < NBUCK) {
        const int run = lh[t];
        gbase[t] = (run > 0) ? atomicAdd(&gcur[t], run) : 0;
        lcur[t] = 0;
    }
    __syncthreads();
#pragma unroll
    for (int j = 0; j < 8; ++j) {
        const int bk = b8[j];
        if (bk >= 0) {
            const int p = atomicAdd(&lcur[bk], 1);
            ebuf[bk * BCAP + gbase[bk] + p] = v8[j];
        }
    }
}

// ---------------------------------------------------------------------------
// fill: one block per bucket. Local 256-node hist+scan; cnt/row_ptr/csr.
// ---------------------------------------------------------------------------
__global__ __launch_bounds__(256) void fill_kernel(
    const int* __restrict__ ebuf, const int* __restrict__ gcur,
    int* __restrict__ cnt, int* __restrict__ row_ptr, int* __restrict__ csr)
{
    __shared__ int lh[256], loff[256], lcur[256];
    const int b = blockIdx.x;
    const int t = threadIdx.x;
    const int e0 = b * BCAP;
    const int nb = gcur[b];
    lh[t] = 0;
    __syncthreads();
    for (int i = t; i < nb; i += 256) atomicAdd(&lh[ebuf[e0 + i] & 255], 1);
    __syncthreads();
    const int v = lh[t];
    loff[t] = v;
    __syncthreads();
    for (int off = 1; off < 256; off <<= 1) {
        const int add = (t >= off) ? loff[t - off] : 0;
        __syncthreads();
        loff[t] += add;
        __syncthreads();
    }
    const int ex = loff[t] - v;
    const int node = b * 256 + t;
    if (node < N_NODES) { cnt[node] = v; row_ptr[node] = e0 + ex; }
    lcur[t] = ex;
    __syncthreads();
    for (int i = t; i < nb; i += 256) {
        const int pr = ebuf[e0 + i];
        const int p = atomicAdd(&lcur[pr & 255], 1);
        csr[e0 + p] = pr >> 8;
    }
}

// ---------------------------------------------------------------------------
// l2f: fused agg1 + mm2. One block per 64-node tile.
// Phase A: gather-mean fp8 p1 rows (16 lanes/node, uint2 = 8 fp8 ch/lane),
//          h = relu(mean + b1 + t1) -> bf16 into LDS (stride 136 ushorts).
// Phase B: MFMA h @ W2l / h @ W2r from LDS -> p2b, t2b (bf16).
// ---------------------------------------------------------------------------
__global__ __launch_bounds__(256) void l2f_kernel(
    const uchar_t* __restrict__ p1f, const ushort_t* __restrict__ t1b,
    const float* __restrict__ b1, const int* __restrict__ row_ptr,
    const int* __restrict__ cnt, const int* __restrict__ csr,
    const ushort_t* __restrict__ wpack,
    ushort_t* __restrict__ p2b, ushort_t* __restrict__ t2b)
{
    __shared__ ushort_t hs[64 * HS_STRIDE];
    const int blk = blockIdx.x;
    const int wv  = threadIdx.x >> 6;
    const int g   = (threadIdx.x >> 4) & 3;     // 16-lane group within wave
    const int c8  = threadIdx.x & 15;           // channels 8*c8 .. 8*c8+7
    const uint2* p1v = (const uint2*)p1f;       // row stride 16 uint2

#pragma unroll
    for (int p = 0; p < 4; ++p) {
        const int nl   = p * 16 + wv * 4 + g;   // local node 0..63
        const int node = blk * 64 + nl;
        float a0=0,a1=0,a2=0,a3=0,a4=0,a5=0,a6=0,a7=0;
        int degi = 0;
        if (node < N_NODES) {
            const int start = row_ptr[node];
            degi = cnt[node];
            int e = 0;
            for (; e + 3 < degi; e += 4) {
                const int s0 = csr[start + e];
                const int s1 = csr[start + e + 1];
                const int s2 = csr[start + e + 2];
                const int s3 = csr[start + e + 3];
                const uint2 v0 = p1v[(size_t)s0 * 16 + c8];
                const uint2 v1 = p1v[(size_t)s1 * 16 + c8];
                const uint2 v2 = p1v[(size_t)s2 * 16 + c8];
                const uint2 v3 = p1v[(size_t)s3 * 16 + c8];
#pragma unroll
                for (int q = 0; q < 4; ++q) {
                    const uint2 v = (q == 0) ? v0 : (q == 1) ? v1 : (q == 2) ? v2 : v3;
                    const f32x2 lx = __builtin_amdgcn_cvt_pk_f32_fp8((int)v.x, false);
                    const f32x2 hx = __builtin_amdgcn_cvt_pk_f32_fp8((int)v.x, true);
                    const f32x2 ly = __builtin_amdgcn_cvt_pk_f32_fp8((int)v.y, false);
                    const f32x2 hy = __builtin_amdgcn_cvt_pk_f32_fp8((int)v.y, true);
                    a0 += lx.x; a1 += lx.y; a2 += hx.x; a3 += hx.y;
                    a4 += ly.x; a5 += ly.y; a6 += hy.x; a7 += hy.y;
                }
            }
            for (; e < degi; ++e) {
                const uint2 v = p1v[(size_t)csr[start + e] * 16 + c8];
                const f32x2 lx = __builtin_amdgcn_cvt_pk_f32_fp8((int)v.x, false);
                const f32x2 hx = __builtin_amdgcn_cvt_pk_f32_fp8((int)v.x, true);
                const f32x2 ly = __builtin_amdgcn_cvt_pk_f32_fp8((int)v.y, false);
                const f32x2 hy = __builtin_amdgcn_cvt_pk_f32_fp8((int)v.y, true);
                a0 += lx.x; a1 += lx.y; a2 += hx.x; a3 += hx.y;
                a4 += ly.x; a5 += ly.y; a6 += hy.x; a7 += hy.y;
            }
        }
        uint4 o = make_uint4(0u, 0u, 0u, 0u);
        if (node < N_NODES) {
            const float inv = 1.0f / fmaxf((float)degi, 1.0f);
            const size_t i = (size_t)node * HID_C + c8 * 8;
            const uint4 tv = *(const uint4*)(t1b + i);
            const float4 bL = *(const float4*)(b1 + c8 * 8);
            const float4 bH = *(const float4*)(b1 + c8 * 8 + 4);
            const float r0 = fmaxf(fmaf(a0, inv, bL.x + bflo(tv.x)), 0.0f);
            const float r1 = fmaxf(fmaf(a1, inv, bL.y + bfhi(tv.x)), 0.0f);
            const float r2 = fmaxf(fmaf(a2, inv, bL.z + bflo(tv.y)), 0.0f);
            const float r3 = fmaxf(fmaf(a3, inv, bL.w + bfhi(tv.y)), 0.0f);
            const float r4 = fmaxf(fmaf(a4, inv, bH.x + bflo(tv.z)), 0.0f);
            const float r5 = fmaxf(fmaf(a5, inv, bH.y + bfhi(tv.z)), 0.0f);
            const float r6 = fmaxf(fmaf(a6, inv, bH.z + bflo(tv.w)), 0.0f);
            const float r7 = fmaxf(fmaf(a7, inv, bH.w + bfhi(tv.w)), 0.0f);
            o.x = (uint_t)f2bf(r0) | ((uint_t)f2bf(r1) << 16);
            o.y = (uint_t)f2bf(r2) | ((uint_t)f2bf(r3) << 16);
            o.z = (uint_t)f2bf(r4) | ((uint_t)f2bf(r5) << 16);
            o.w = (uint_t)f2bf(r6) | ((uint_t)f2bf(r7) << 16);
        }
        *(uint4*)&hs[nl * HS_STRIDE + c8 * 8] = o;
    }
    __syncthreads();

    // Phase B: MFMA. Wave wv owns rows wv*16..wv*16+15.
    const int lane = threadIdx.x & 63;
    const int quad = lane >> 4;
    const int m    = lane & 15;
    const int row0 = blk * 64 + wv * 16;

    const bf16x8* Bl = (const bf16x8*)(wpack + 32768);
    const bf16x8* Br = (const bf16x8*)(wpack + 40960);

    f32x4 accl[4], accr[4];
#pragma unroll
    for (int ct = 0; ct < 4; ++ct) { accl[ct] = (f32x4)(0.0f); accr[ct] = (f32x4)(0.0f); }

#pragma unroll
    for (int kt = 0; kt < 4; ++kt) {
        const bf16x8 af = *(const bf16x8*)&hs[(wv * 16 + m) * HS_STRIDE + kt * 32 + quad * 8];
#pragma unroll
        for (int ct = 0; ct < 4; ++ct) {
            const bf16x8 bl = Bl[(ct * 4 + kt) * 64 + lane];
            const bf16x8 br = Br[(ct * 4 + kt) * 64 + lane];
            accl[ct] = __builtin_amdgcn_mfma_f32_16x16x32_bf16(af, bl, accl[ct], 0, 0, 0);
            accr[ct] = __builtin_amdgcn_mfma_f32_16x16x32_bf16(af, br, accr[ct], 0, 0, 0);
        }
    }

#pragma unroll
    for (int r = 0; r < 4; ++r) {
        const int orow = row0 + quad * 4 + r;
        if (orow < N_NODES) {
#pragma unroll
            for (int ct = 0; ct < 4; ++ct) {
                const int col = ct * 16 + m;
                p2b[(size_t)orow * OUT_C + col] = f2bf(accl[ct][r]);
                t2b[(size_t)orow * OUT_C + col] = f2bf(accr[ct][r]);
            }
        }
    }
}

// ---------------------------------------------------------------------------
// agg2: 16 nodes/block, 16 lanes/node, uint2 loads (4 bf16 ch/lane).
// out = mean(p2[src]) + b2 + t2.
// ---------------------------------------------------------------------------
__global__ __launch_bounds__(256) void agg2_kernel(
    const ushort_t* __restrict__ p2b, const ushort_t* __restrict__ t2b,
    const float* __restrict__ b2, const int* __restrict__ row_ptr,
    const int* __restrict__ cnt, const int* __restrict__ csr,
    float* __restrict__ out)
{
    const int wv  = threadIdx.x >> 6;
    const int g   = (threadIdx.x >> 4) & 3;
    const int c4  = threadIdx.x & 15;          // channels 4*c4 .. 4*c4+3
    const int node = blockIdx.x * 16 + wv * 4 + g;
    const int start = row_ptr[node];
    const int degi  = cnt[node];
    const uint2* p2v = (const uint2*)p2b;      // row stride 16 uint2

    float a0 = 0.0f, a1 = 0.0f, a2 = 0.0f, a3 = 0.0f;
    int e = 0;
    for (; e + 3 < degi; e += 4) {
        const int s0 = csr[start + e];
        const int s1 = csr[start + e + 1];
        const int s2 = csr[start + e + 2];
        const int s3 = csr[start + e + 3];
        const uint2 v0 = p2v[(size_t)s0 * 16 + c4];
        const uint2 v1 = p2v[(size_t)s1 * 16 + c4];
        const uint2 v2 = p2v[(size_t)s2 * 16 + c4];
        const uint2 v3 = p2v[(size_t)s3 * 16 + c4];
        a0 += bflo(v0.x) + bflo(v1.x) + bflo(v2.x) + bflo(v3.x);
        a1 += bfhi(v0.x) + bfhi(v1.x) + bfhi(v2.x) + bfhi(v3.x);
        a2 += bflo(v0.y) + bflo(v1.y) + bflo(v2.y) + bflo(v3.y);
        a3 += bfhi(v0.y) + bfhi(v1.y) + bfhi(v2.y) + bfhi(v3.y);
    }
    for (; e < degi; ++e) {
        const uint2 v0 = p2v[(size_t)csr[start + e] * 16 + c4];
        a0 += bflo(v0.x); a1 += bfhi(v0.x);
        a2 += bflo(v0.y); a3 += bfhi(v0.y);
    }

    const float inv = 1.0f / fmaxf((float)degi, 1.0f);
    const size_t i = (size_t)node * OUT_C + c4 * 4;
    const uint2 tv = *(const uint2*)(t2b + i);
    const float4 bv = *(const float4*)(b2 + c4 * 4);
    float4 o;
    o.x = fmaf(a0, inv, bv.x + bflo(tv.x));
    o.y = fmaf(a1, inv, bv.y + bfhi(tv.x));
    o.z = fmaf(a2, inv, bv.z + bflo(tv.y));
    o.w = fmaf(a3, inv, bv.w + bfhi(tv.y));
    *(float4*)(out + i) = o;
}

extern "C" void kernel_launch(void* const* d_in, const int* in_sizes, int n_in,
                              void* d_out, int out_size, void* d_ws, size_t ws_size,
                              hipStream_t stream)
{
    const float* x   = (const float*)d_in[0];
    const int*   ei  = (const int*)d_in[1];
    const float* W1l = (const float*)d_in[2];
    const float* b1  = (const float*)d_in[3];
    const float* W1r = (const float*)d_in[4];
    const float* W2l = (const float*)d_in[5];
    const float* b2  = (const float*)d_in[6];
    const float* W2r = (const float*)d_in[7];
    float* out = (float*)d_out;

    const int* src = ei;
    const int* dst = ei + N_EDGES;

    const size_t NH = (size_t)N_NODES * HID_C;   // 6.4M
    const size_t NO = (size_t)N_NODES * OUT_C;   // 3.2M
    const size_t EB = (size_t)NBUCK * BCAP;      // 1.204M slots

    // Workspace layout (8B-aligned first).
    char* ws = (char*)d_ws;
    ushort_t* t1b   = (ushort_t*)ws;                   ws += NH * sizeof(ushort_t);
    ushort_t* t2b   = (ushort_t*)ws;                   ws += NO * sizeof(ushort_t);
    ushort_t* p2b   = (ushort_t*)ws;                   ws += NO * sizeof(ushort_t);
    ushort_t* wpack = (ushort_t*)ws;                   ws += 49152 * sizeof(ushort_t);
    int* ebuf    = (int*)ws;                           ws += EB * sizeof(int);
    int* csr     = (int*)ws;                           ws += EB * sizeof(int);
    int* cnt     = (int*)ws;                           ws += N_NODES * sizeof(int);
    int* row_ptr = (int*)ws;                           ws += N_NODES * sizeof(int);
    int* gcur    = (int*)ws;                           ws += NBUCK * sizeof(int);
    uchar_t* p1f = (uchar_t*)ws;                       ws += NH * sizeof(uchar_t);

    const size_t need = (size_t)(ws - (char*)d_ws);
    if (ws_size < need) return;

    // K0: pack weights | zero bucket cursors        (input-only)
    k0_kernel<<<PACK_BLKS + 1, 256, 0, stream>>>(W1l, W1r, W2l, W2r, wpack, gcur);
    // K1: mm1 | bucket scatter                      (reads only K0 outputs/inputs)
    k1_kernel<<<MM1_BLKS + EBLKS, 256, 0, stream>>>(
        x, wpack, p1f, t1b, src, dst, gcur, ebuf);
    // CSR finalize
    fill_kernel<<<NBUCK, 256, 0, stream>>>(ebuf, gcur, cnt, row_ptr, csr);
    // Fused agg1 + mm2 (h lives only in LDS)
    l2f_kernel<<<MM1_BLKS, 256, 0, stream>>>(
        p1f, t1b, b1, row_ptr, cnt, csr, wpack, p2b, t2b);
    // Final aggregation
    agg2_kernel<<<(N_NODES + 15) / 16, 256, 0, stream>>>(
        p2b, t2b, b2, row_ptr, cnt, csr, out);
}

// Round 9
// 175.040 us; speedup vs baseline: 1.2569x; 1.0123x over previous
//
#include <hip/hip_runtime.h>

#define N_NODES 50000
#define N_EDGES 800000
#define IN_C    128
#define HID_C   128
#define OUT_C   64
#define NBUCK   196                         // ceil(50000/256) buckets of 256 nodes
#define BCAP    6144                        // fixed slots/bucket (mean 4082 -> 32 sigma headroom)
#define EPB     2048                        // edges per scatter block
#define EBLKS   ((N_EDGES + EPB - 1) / EPB) // 391
#define PACK_BLKS 192
#define MM1_BLKS  ((N_NODES + 63) / 64)     // 782
#define HS_STRIDE 136                       // 128 ushorts + 8 pad -> 272B rows

typedef unsigned short ushort_t;
typedef unsigned int   uint_t;
typedef unsigned char  uchar_t;
typedef __attribute__((ext_vector_type(8))) short bf16x8;
typedef __attribute__((ext_vector_type(4))) float f32x4;
typedef __attribute__((ext_vector_type(2))) float f32x2;

__device__ inline ushort_t f2bf(float f) {
    uint_t u = __float_as_uint(f);
    uint_t r = (u + 0x7fffu + ((u >> 16) & 1u)) >> 16;
    return (ushort_t)r;
}
__device__ inline float bflo(uint_t v) { return __uint_as_float(v << 16); }
__device__ inline float bfhi(uint_t v) { return __uint_as_float(v & 0xffff0000u); }
__device__ inline uchar_t f2fp8(float v) {
    return (uchar_t)(__builtin_amdgcn_cvt_pk_fp8_f32(v, v, 0, false) & 0xff);
}

// ---------------------------------------------------------------------------
// Weight pre-pack into B-fragment order for mfma_f32_16x16x32_bf16.
// ---------------------------------------------------------------------------
__device__ inline void pack_one(const float* W, ushort_t* Wp, int K, int N, int idx) {
    const int j  = idx & 7;
    const int L  = (idx >> 3) & 63;
    const int t  = idx >> 9;
    const int KT = K / 32;
    const int kt = t % KT;
    const int ct = t / KT;
    const int k  = kt * 32 + (L >> 4) * 8 + j;
    const int n  = ct * 16 + (L & 15);
    Wp[idx] = f2bf(W[k * N + n]);
}

// ---------------------------------------------------------------------------
// K0: pack weights (blocks 0..191) | zero bucket cursors (block 192).
// ---------------------------------------------------------------------------
__global__ __launch_bounds__(256) void k0_kernel(
    const float* __restrict__ W1l, const float* __restrict__ W1r,
    const float* __restrict__ W2l, const float* __restrict__ W2r,
    ushort_t* __restrict__ wpack, int* __restrict__ gcur)
{
    const int b = blockIdx.x;
    if (b < PACK_BLKS) {
        const int tid = b * 256 + threadIdx.x;
        if (tid < 16384)      pack_one(W1l, wpack,          IN_C,  HID_C, tid);
        else if (tid < 32768) pack_one(W1r, wpack + 16384,  IN_C,  HID_C, tid - 16384);
        else if (tid < 40960) pack_one(W2l, wpack + 32768,  HID_C, OUT_C, tid - 32768);
        else if (tid < 49152) pack_one(W2r, wpack + 40960,  HID_C, OUT_C, tid - 40960);
    } else {
        if (threadIdx.x < NBUCK) gcur[threadIdx.x] = 0;
    }
}

// ---------------------------------------------------------------------------
// mm1 body: p1f = fp8(x @ W1l), t1b = bf16(x @ W1r). wpack from K0.
// ---------------------------------------------------------------------------
__device__ inline void mm1_body(int bid, const float* __restrict__ x,
                                const ushort_t* __restrict__ wpack,
                                uchar_t* __restrict__ p1f, ushort_t* __restrict__ t1b)
{
    const int wave = threadIdx.x >> 6;
    const int lane = threadIdx.x & 63;
    const int quad = lane >> 4;
    const int m    = lane & 15;
    const int row0 = bid * 64 + wave * 16;
    const int arow = min(row0 + m, N_NODES - 1);

    const bf16x8* Bl = (const bf16x8*)(wpack);
    const bf16x8* Br = (const bf16x8*)(wpack + 16384);

    f32x4 accl[8], accr[8];
#pragma unroll
    for (int ct = 0; ct < 8; ++ct) { accl[ct] = (f32x4)(0.0f); accr[ct] = (f32x4)(0.0f); }

#pragma unroll
    for (int kt = 0; kt < 4; ++kt) {
        const float* xp = x + (size_t)arow * IN_C + kt * 32 + quad * 8;
        const float4 a0 = *(const float4*)(xp);
        const float4 a1 = *(const float4*)(xp + 4);
        bf16x8 af;
        af[0] = (short)f2bf(a0.x); af[1] = (short)f2bf(a0.y);
        af[2] = (short)f2bf(a0.z); af[3] = (short)f2bf(a0.w);
        af[4] = (short)f2bf(a1.x); af[5] = (short)f2bf(a1.y);
        af[6] = (short)f2bf(a1.z); af[7] = (short)f2bf(a1.w);
#pragma unroll
        for (int ct = 0; ct < 8; ++ct) {
            const bf16x8 bl = Bl[(ct * 4 + kt) * 64 + lane];
            const bf16x8 br = Br[(ct * 4 + kt) * 64 + lane];
            accl[ct] = __builtin_amdgcn_mfma_f32_16x16x32_bf16(af, bl, accl[ct], 0, 0, 0);
            accr[ct] = __builtin_amdgcn_mfma_f32_16x16x32_bf16(af, br, accr[ct], 0, 0, 0);
        }
    }

#pragma unroll
    for (int r = 0; r < 4; ++r) {
        const int orow = row0 + quad * 4 + r;
        if (orow < N_NODES) {
#pragma unroll
            for (int ct = 0; ct < 8; ++ct) {
                const int col = ct * 16 + m;
                p1f[(size_t)orow * HID_C + col] = f2fp8(accl[ct][r]);
                t1b[(size_t)orow * HID_C + col] = f2bf(accr[ct][r]);
            }
        }
    }
}

// ---------------------------------------------------------------------------
// K1: mm1 (blocks 0..781) | bucket scatter (blocks 782..1172).
// Scatter: int4 edge loads; LDS hist -> claim run per bucket -> packed words.
// ---------------------------------------------------------------------------
__global__ __launch_bounds__(256) void k1_kernel(
    const float* __restrict__ x, const ushort_t* __restrict__ wpack,
    uchar_t* __restrict__ p1f, ushort_t* __restrict__ t1b,
    const int* __restrict__ src, const int* __restrict__ dst,
    int* gcur, int* __restrict__ ebuf)
{
    __shared__ int lh[256], gbase[256], lcur[256];
    const int b = blockIdx.x;
    if (b < MM1_BLKS) {
        mm1_body(b, x, wpack, p1f, t1b);
        return;
    }
    const int blk = b - MM1_BLKS;
    const int t = threadIdx.x;
    lh[t] = 0;
    __syncthreads();
    const int e0 = blk * EPB + t * 8;        // N_EDGES % 8 == 0 -> chunk all-or-nothing
    int v8[8], b8[8];
    if (e0 < N_EDGES) {
        const int4 sa = *(const int4*)&src[e0];
        const int4 sb = *(const int4*)&src[e0 + 4];
        const int4 da = *(const int4*)&dst[e0];
        const int4 db = *(const int4*)&dst[e0 + 4];
        const int s8a[8] = {sa.x, sa.y, sa.z, sa.w, sb.x, sb.y, sb.z, sb.w};
        const int d8a[8] = {da.x, da.y, da.z, da.w, db.x, db.y, db.z, db.w};
#pragma unroll
        for (int j = 0; j < 8; ++j) {
            b8[j] = d8a[j] >> 8;
            v8[j] = (s8a[j] << 8) | (d8a[j] & 255);
            atomicAdd(&lh[b8[j]], 1);
        }
    } else {
#pragma unroll
        for (int j = 0; j < 8; ++j) b8[j] = -1;
    }
    __syncthreads();
    if (t < NBUCK) {
        const int run = lh[t];
        gbase[t] = (run > 0) ? atomicAdd(&gcur[t], run) : 0;
        lcur[t] = 0;
    }
    __syncthreads();
#pragma unroll
    for (int j = 0; j < 8; ++j) {
        const int bk = b8[j];
        if (bk >= 0) {
            const int p = atomicAdd(&lcur[bk], 1);
            ebuf[bk * BCAP + gbase[bk] + p] = v8[j];
        }
    }
}

// ---------------------------------------------------------------------------
// fill: one block per bucket. Local 256-node hist+scan; cnt/row_ptr/csr.
// ---------------------------------------------------------------------------
__global__ __launch_bounds__(256) void fill_kernel(
    const int* __restrict__ ebuf, const int* __restrict__ gcur,
    int* __restrict__ cnt, int* __restrict__ row_ptr, int* __restrict__ csr)
{
    __shared__ int lh[256], loff[256], lcur[256];
    const int b = blockIdx.x;
    const int t = threadIdx.x;
    const int e0 = b * BCAP;
    const int nb = gcur[b];
    lh[t] = 0;
    __syncthreads();
    for (int i = t; i < nb; i += 256) atomicAdd(&lh[ebuf[e0 + i] & 255], 1);
    __syncthreads();
    const int v = lh[t];
    loff[t] = v;
    __syncthreads();
    for (int off = 1; off < 256; off <<= 1) {
        const int add = (t >= off) ? loff[t - off] : 0;
        __syncthreads();
        loff[t] += add;
        __syncthreads();
    }
    const int ex = loff[t] - v;
    const int node = b * 256 + t;
    if (node < N_NODES) { cnt[node] = v; row_ptr[node] = e0 + ex; }
    lcur[t] = ex;
    __syncthreads();
    for (int i = t; i < nb; i += 256) {
        const int pr = ebuf[e0 + i];
        const int p = atomicAdd(&lcur[pr & 255], 1);
        csr[e0 + p] = pr >> 8;
    }
}

// ---------------------------------------------------------------------------
// l2f: fused agg1 + mm2. One block per 64-node tile.
// Phase A: 16-lane groups pop nodes from an LDS pool (dynamic balance),
//          gather-mean fp8 p1 rows (uint2/lane), h=relu(mean+b1+t1) -> LDS bf16.
// Phase B: MFMA h @ W2l / h @ W2r from LDS -> p2f (fp8), t2b (bf16).
// ---------------------------------------------------------------------------
__global__ __launch_bounds__(256) void l2f_kernel(
    const uchar_t* __restrict__ p1f, const ushort_t* __restrict__ t1b,
    const float* __restrict__ b1, const int* __restrict__ row_ptr,
    const int* __restrict__ cnt, const int* __restrict__ csr,
    const ushort_t* __restrict__ wpack,
    uchar_t* __restrict__ p2f, ushort_t* __restrict__ t2b)
{
    __shared__ ushort_t hs[64 * HS_STRIDE];
    __shared__ int pool;
    if (threadIdx.x == 0) pool = 0;
    __syncthreads();

    const int blk   = blockIdx.x;
    const int lanew = threadIdx.x & 63;
    const int gb    = lanew & 48;               // group leader lane in wave
    const int c8    = threadIdx.x & 15;         // channels 8*c8 .. 8*c8+7
    const uint2* p1v = (const uint2*)p1f;       // row stride 16 uint2

    while (true) {
        int nl = 0;
        if (c8 == 0) nl = atomicAdd(&pool, 1);
        nl = __shfl(nl, gb, 64);
        if (nl >= 64) break;
        const int node = blk * 64 + nl;
        uint4 o = make_uint4(0u, 0u, 0u, 0u);
        if (node < N_NODES) {
            const int start = row_ptr[node];
            const int degi  = cnt[node];
            float a0=0,a1=0,a2=0,a3=0,a4=0,a5=0,a6=0,a7=0;
            int e = 0;
            for (; e + 3 < degi; e += 4) {
                const int s0 = csr[start + e];
                const int s1 = csr[start + e + 1];
                const int s2 = csr[start + e + 2];
                const int s3 = csr[start + e + 3];
                const uint2 v0 = p1v[(size_t)s0 * 16 + c8];
                const uint2 v1 = p1v[(size_t)s1 * 16 + c8];
                const uint2 v2 = p1v[(size_t)s2 * 16 + c8];
                const uint2 v3 = p1v[(size_t)s3 * 16 + c8];
#pragma unroll
                for (int q = 0; q < 4; ++q) {
                    const uint2 v = (q == 0) ? v0 : (q == 1) ? v1 : (q == 2) ? v2 : v3;
                    const f32x2 lx = __builtin_amdgcn_cvt_pk_f32_fp8((int)v.x, false);
                    const f32x2 hx = __builtin_amdgcn_cvt_pk_f32_fp8((int)v.x, true);
                    const f32x2 ly = __builtin_amdgcn_cvt_pk_f32_fp8((int)v.y, false);
                    const f32x2 hy = __builtin_amdgcn_cvt_pk_f32_fp8((int)v.y, true);
                    a0 += lx.x; a1 += lx.y; a2 += hx.x; a3 += hx.y;
                    a4 += ly.x; a5 += ly.y; a6 += hy.x; a7 += hy.y;
                }
            }
            for (; e < degi; ++e) {
                const uint2 v = p1v[(size_t)csr[start + e] * 16 + c8];
                const f32x2 lx = __builtin_amdgcn_cvt_pk_f32_fp8((int)v.x, false);
                const f32x2 hx = __builtin_amdgcn_cvt_pk_f32_fp8((int)v.x, true);
                const f32x2 ly = __builtin_amdgcn_cvt_pk_f32_fp8((int)v.y, false);
                const f32x2 hy = __builtin_amdgcn_cvt_pk_f32_fp8((int)v.y, true);
                a0 += lx.x; a1 += lx.y; a2 += hx.x; a3 += hx.y;
                a4 += ly.x; a5 += ly.y; a6 += hy.x; a7 += hy.y;
            }
            const float inv = 1.0f / fmaxf((float)degi, 1.0f);
            const size_t i = (size_t)node * HID_C + c8 * 8;
            const uint4 tv = *(const uint4*)(t1b + i);
            const float4 bL = *(const float4*)(b1 + c8 * 8);
            const float4 bH = *(const float4*)(b1 + c8 * 8 + 4);
            const float r0 = fmaxf(fmaf(a0, inv, bL.x + bflo(tv.x)), 0.0f);
            const float r1 = fmaxf(fmaf(a1, inv, bL.y + bfhi(tv.x)), 0.0f);
            const float r2 = fmaxf(fmaf(a2, inv, bL.z + bflo(tv.y)), 0.0f);
            const float r3 = fmaxf(fmaf(a3, inv, bL.w + bfhi(tv.y)), 0.0f);
            const float r4 = fmaxf(fmaf(a4, inv, bH.x + bflo(tv.z)), 0.0f);
            const float r5 = fmaxf(fmaf(a5, inv, bH.y + bfhi(tv.z)), 0.0f);
            const float r6 = fmaxf(fmaf(a6, inv, bH.z + bflo(tv.w)), 0.0f);
            const float r7 = fmaxf(fmaf(a7, inv, bH.w + bfhi(tv.w)), 0.0f);
            o.x = (uint_t)f2bf(r0) | ((uint_t)f2bf(r1) << 16);
            o.y = (uint_t)f2bf(r2) | ((uint_t)f2bf(r3) << 16);
            o.z = (uint_t)f2bf(r4) | ((uint_t)f2bf(r5) << 16);
            o.w = (uint_t)f2bf(r6) | ((uint_t)f2bf(r7) << 16);
        }
        *(uint4*)&hs[nl * HS_STRIDE + c8 * 8] = o;
    }
    __syncthreads();

    // Phase B: MFMA. Wave wv owns rows wv*16..wv*16+15.
    const int wv   = threadIdx.x >> 6;
    const int lane = threadIdx.x & 63;
    const int quad = lane >> 4;
    const int m    = lane & 15;
    const int row0 = blk * 64 + wv * 16;

    const bf16x8* Bl = (const bf16x8*)(wpack + 32768);
    const bf16x8* Br = (const bf16x8*)(wpack + 40960);

    f32x4 accl[4], accr[4];
#pragma unroll
    for (int ct = 0; ct < 4; ++ct) { accl[ct] = (f32x4)(0.0f); accr[ct] = (f32x4)(0.0f); }

#pragma unroll
    for (int kt = 0; kt < 4; ++kt) {
        const bf16x8 af = *(const bf16x8*)&hs[(wv * 16 + m) * HS_STRIDE + kt * 32 + quad * 8];
#pragma unroll
        for (int ct = 0; ct < 4; ++ct) {
            const bf16x8 bl = Bl[(ct * 4 + kt) * 64 + lane];
            const bf16x8 br = Br[(ct * 4 + kt) * 64 + lane];
            accl[ct] = __builtin_amdgcn_mfma_f32_16x16x32_bf16(af, bl, accl[ct], 0, 0, 0);
            accr[ct] = __builtin_amdgcn_mfma_f32_16x16x32_bf16(af, br, accr[ct], 0, 0, 0);
        }
    }

#pragma unroll
    for (int r = 0; r < 4; ++r) {
        const int orow = row0 + quad * 4 + r;
        if (orow < N_NODES) {
#pragma unroll
            for (int ct = 0; ct < 4; ++ct) {
                const int col = ct * 16 + m;
                p2f[(size_t)orow * OUT_C + col] = f2fp8(accl[ct][r]);
                t2b[(size_t)orow * OUT_C + col] = f2bf(accr[ct][r]);
            }
        }
    }
}

// ---------------------------------------------------------------------------
// agg2: 64 nodes/block, 8 lanes/node (fp8 rows = 64B = 8 x uint2).
// out = mean(p2[src]) + b2 + t2.
// ---------------------------------------------------------------------------
__global__ __launch_bounds__(256) void agg2_kernel(
    const uchar_t* __restrict__ p2f, const ushort_t* __restrict__ t2b,
    const float* __restrict__ b2, const int* __restrict__ row_ptr,
    const int* __restrict__ cnt, const int* __restrict__ csr,
    float* __restrict__ out)
{
    const int c8  = threadIdx.x & 7;           // channels 8*c8 .. 8*c8+7
    const int grp = threadIdx.x >> 3;          // 0..31
    const uint2* p2v = (const uint2*)p2f;      // row stride 8 uint2

#pragma unroll
    for (int p = 0; p < 2; ++p) {
        const int node = blockIdx.x * 64 + p * 32 + grp;
        if (node >= N_NODES) continue;
        const int start = row_ptr[node];
        const int degi  = cnt[node];
        float a0=0,a1=0,a2=0,a3=0,a4=0,a5=0,a6=0,a7=0;
        int e = 0;
        for (; e + 3 < degi; e += 4) {
            const int s0 = csr[start + e];
            const int s1 = csr[start + e + 1];
            const int s2 = csr[start + e + 2];
            const int s3 = csr[start + e + 3];
            const uint2 v0 = p2v[(size_t)s0 * 8 + c8];
            const uint2 v1 = p2v[(size_t)s1 * 8 + c8];
            const uint2 v2 = p2v[(size_t)s2 * 8 + c8];
            const uint2 v3 = p2v[(size_t)s3 * 8 + c8];
#pragma unroll
            for (int q = 0; q < 4; ++q) {
                const uint2 v = (q == 0) ? v0 : (q == 1) ? v1 : (q == 2) ? v2 : v3;
                const f32x2 lx = __builtin_amdgcn_cvt_pk_f32_fp8((int)v.x, false);
                const f32x2 hx = __builtin_amdgcn_cvt_pk_f32_fp8((int)v.x, true);
                const f32x2 ly = __builtin_amdgcn_cvt_pk_f32_fp8((int)v.y, false);
                const f32x2 hy = __builtin_amdgcn_cvt_pk_f32_fp8((int)v.y, true);
                a0 += lx.x; a1 += lx.y; a2 += hx.x; a3 += hx.y;
                a4 += ly.x; a5 += ly.y; a6 += hy.x; a7 += hy.y;
            }
        }
        for (; e < degi; ++e) {
            const uint2 v = p2v[(size_t)csr[start + e] * 8 + c8];
            const f32x2 lx = __builtin_amdgcn_cvt_pk_f32_fp8((int)v.x, false);
            const f32x2 hx = __builtin_amdgcn_cvt_pk_f32_fp8((int)v.x, true);
            const f32x2 ly = __builtin_amdgcn_cvt_pk_f32_fp8((int)v.y, false);
            const f32x2 hy = __builtin_amdgcn_cvt_pk_f32_fp8((int)v.y, true);
            a0 += lx.x; a1 += lx.y; a2 += hx.x; a3 += hx.y;
            a4 += ly.x; a5 += ly.y; a6 += hy.x; a7 += hy.y;
        }

        const float inv = 1.0f / fmaxf((float)degi, 1.0f);
        const size_t i = (size_t)node * OUT_C + c8 * 8;
        const uint4 tv = *(const uint4*)(t2b + i);
        const float4 bL = *(const float4*)(b2 + c8 * 8);
        const float4 bH = *(const float4*)(b2 + c8 * 8 + 4);
        float4 oL, oH;
        oL.x = fmaf(a0, inv, bL.x + bflo(tv.x));
        oL.y = fmaf(a1, inv, bL.y + bfhi(tv.x));
        oL.z = fmaf(a2, inv, bL.z + bflo(tv.y));
        oL.w = fmaf(a3, inv, bL.w + bfhi(tv.y));
        oH.x = fmaf(a4, inv, bH.x + bflo(tv.z));
        oH.y = fmaf(a5, inv, bH.y + bfhi(tv.z));
        oH.z = fmaf(a6, inv, bH.z + bflo(tv.w));
        oH.w = fmaf(a7, inv, bH.w + bfhi(tv.w));
        *(float4*)(out + i) = oL;
        *(float4*)(out + i + 4) = oH;
    }
}

extern "C" void kernel_launch(void* const* d_in, const int* in_sizes, int n_in,
                              void* d_out, int out_size, void* d_ws, size_t ws_size,
                              hipStream_t stream)
{
    const float* x   = (const float*)d_in[0];
    const int*   ei  = (const int*)d_in[1];
    const float* W1l = (const float*)d_in[2];
    const float* b1  = (const float*)d_in[3];
    const float* W1r = (const float*)d_in[4];
    const float* W2l = (const float*)d_in[5];
    const float* b2  = (const float*)d_in[6];
    const float* W2r = (const float*)d_in[7];
    float* out = (float*)d_out;

    const int* src = ei;
    const int* dst = ei + N_EDGES;

    const size_t NH = (size_t)N_NODES * HID_C;   // 6.4M
    const size_t NO = (size_t)N_NODES * OUT_C;   // 3.2M
    const size_t EB = (size_t)NBUCK * BCAP;      // 1.204M slots

    // Workspace layout (8B-aligned first, bytes last).
    char* ws = (char*)d_ws;
    ushort_t* t1b   = (ushort_t*)ws;                   ws += NH * sizeof(ushort_t);
    ushort_t* t2b   = (ushort_t*)ws;                   ws += NO * sizeof(ushort_t);
    ushort_t* wpack = (ushort_t*)ws;                   ws += 49152 * sizeof(ushort_t);
    int* ebuf    = (int*)ws;                           ws += EB * sizeof(int);
    int* csr     = (int*)ws;                           ws += EB * sizeof(int);
    int* cnt     = (int*)ws;                           ws += N_NODES * sizeof(int);
    int* row_ptr = (int*)ws;                           ws += N_NODES * sizeof(int);
    int* gcur    = (int*)ws;                           ws += NBUCK * sizeof(int);
    uchar_t* p1f = (uchar_t*)ws;                       ws += NH * sizeof(uchar_t);
    uchar_t* p2f = (uchar_t*)ws;                       ws += NO * sizeof(uchar_t);

    const size_t need = (size_t)(ws - (char*)d_ws);
    if (ws_size < need) return;

    // K0: pack weights | zero bucket cursors        (input-only)
    k0_kernel<<<PACK_BLKS + 1, 256, 0, stream>>>(W1l, W1r, W2l, W2r, wpack, gcur);
    // K1: mm1 | bucket scatter                      (reads only K0 outputs/inputs)
    k1_kernel<<<MM1_BLKS + EBLKS, 256, 0, stream>>>(
        x, wpack, p1f, t1b, src, dst, gcur, ebuf);
    // CSR finalize
    fill_kernel<<<NBUCK, 256, 0, stream>>>(ebuf, gcur, cnt, row_ptr, csr);
    // Fused agg1 + mm2 (h lives only in LDS)
    l2f_kernel<<<MM1_BLKS, 256, 0, stream>>>(
        p1f, t1b, b1, row_ptr, cnt, csr, wpack, p2f, t2b);
    // Final aggregation
    agg2_kernel<<<MM1_BLKS, 256, 0, stream>>>(
        p2f, t2b, b2, row_ptr, cnt, csr, out);
}

// Round 10
// 164.681 us; speedup vs baseline: 1.3360x; 1.0629x over previous
//
#include <hip/hip_runtime.h>

#define N_NODES 50000
#define N_EDGES 800000
#define IN_C    128
#define HID_C   128
#define OUT_C   64
#define NBUCK   196                         // ceil(50000/256) buckets of 256 nodes
#define BCAP    6144                        // fixed slots/bucket (mean 4082 -> 32 sigma headroom)
#define QCAP    1536                        // fixed csr slots per quarter (mean 1024, 16 sigma)
#define EPB     2048                        // edges per scatter block
#define EBLKS   ((N_EDGES + EPB - 1) / EPB) // 391
#define PACK_BLKS 192
#define MM1_BLKS  ((N_NODES + 63) / 64)     // 782
#define L2F_BLKS  (NBUCK * 4)               // 784 quarter-bucket blocks
#define HS_STRIDE 136                       // 128 ushorts + 8 pad -> 272B rows

typedef unsigned short ushort_t;
typedef unsigned int   uint_t;
typedef unsigned char  uchar_t;
typedef __attribute__((ext_vector_type(8))) short bf16x8;
typedef __attribute__((ext_vector_type(4))) float f32x4;
typedef __attribute__((ext_vector_type(2))) float f32x2;

__device__ inline ushort_t f2bf(float f) {
    uint_t u = __float_as_uint(f);
    uint_t r = (u + 0x7fffu + ((u >> 16) & 1u)) >> 16;
    return (ushort_t)r;
}
__device__ inline float bflo(uint_t v) { return __uint_as_float(v << 16); }
__device__ inline float bfhi(uint_t v) { return __uint_as_float(v & 0xffff0000u); }
__device__ inline uchar_t f2fp8(float v) {
    return (uchar_t)(__builtin_amdgcn_cvt_pk_fp8_f32(v, v, 0, false) & 0xff);
}

// ---------------------------------------------------------------------------
// Weight pre-pack into B-fragment order for mfma_f32_16x16x32_bf16.
// ---------------------------------------------------------------------------
__device__ inline void pack_one(const float* W, ushort_t* Wp, int K, int N, int idx) {
    const int j  = idx & 7;
    const int L  = (idx >> 3) & 63;
    const int t  = idx >> 9;
    const int KT = K / 32;
    const int kt = t % KT;
    const int ct = t / KT;
    const int k  = kt * 32 + (L >> 4) * 8 + j;
    const int n  = ct * 16 + (L & 15);
    Wp[idx] = f2bf(W[k * N + n]);
}

// ---------------------------------------------------------------------------
// K0: pack weights (blocks 0..191) | zero bucket cursors (block 192).
// ---------------------------------------------------------------------------
__global__ __launch_bounds__(256) void k0_kernel(
    const float* __restrict__ W1l, const float* __restrict__ W1r,
    const float* __restrict__ W2l, const float* __restrict__ W2r,
    ushort_t* __restrict__ wpack, int* __restrict__ gcur)
{
    const int b = blockIdx.x;
    if (b < PACK_BLKS) {
        const int tid = b * 256 + threadIdx.x;
        if (tid < 16384)      pack_one(W1l, wpack,          IN_C,  HID_C, tid);
        else if (tid < 32768) pack_one(W1r, wpack + 16384,  IN_C,  HID_C, tid - 16384);
        else if (tid < 40960) pack_one(W2l, wpack + 32768,  HID_C, OUT_C, tid - 32768);
        else if (tid < 49152) pack_one(W2r, wpack + 40960,  HID_C, OUT_C, tid - 40960);
    } else {
        if (threadIdx.x < NBUCK) gcur[threadIdx.x] = 0;
    }
}

// ---------------------------------------------------------------------------
// mm1 body: p1f = fp8(x @ W1l), t1b = bf16(x @ W1r). wpack from K0.
// ---------------------------------------------------------------------------
__device__ inline void mm1_body(int bid, const float* __restrict__ x,
                                const ushort_t* __restrict__ wpack,
                                uchar_t* __restrict__ p1f, ushort_t* __restrict__ t1b)
{
    const int wave = threadIdx.x >> 6;
    const int lane = threadIdx.x & 63;
    const int quad = lane >> 4;
    const int m    = lane & 15;
    const int row0 = bid * 64 + wave * 16;
    const int arow = min(row0 + m, N_NODES - 1);

    const bf16x8* Bl = (const bf16x8*)(wpack);
    const bf16x8* Br = (const bf16x8*)(wpack + 16384);

    f32x4 accl[8], accr[8];
#pragma unroll
    for (int ct = 0; ct < 8; ++ct) { accl[ct] = (f32x4)(0.0f); accr[ct] = (f32x4)(0.0f); }

#pragma unroll
    for (int kt = 0; kt < 4; ++kt) {
        const float* xp = x + (size_t)arow * IN_C + kt * 32 + quad * 8;
        const float4 a0 = *(const float4*)(xp);
        const float4 a1 = *(const float4*)(xp + 4);
        bf16x8 af;
        af[0] = (short)f2bf(a0.x); af[1] = (short)f2bf(a0.y);
        af[2] = (short)f2bf(a0.z); af[3] = (short)f2bf(a0.w);
        af[4] = (short)f2bf(a1.x); af[5] = (short)f2bf(a1.y);
        af[6] = (short)f2bf(a1.z); af[7] = (short)f2bf(a1.w);
#pragma unroll
        for (int ct = 0; ct < 8; ++ct) {
            const bf16x8 bl = Bl[(ct * 4 + kt) * 64 + lane];
            const bf16x8 br = Br[(ct * 4 + kt) * 64 + lane];
            accl[ct] = __builtin_amdgcn_mfma_f32_16x16x32_bf16(af, bl, accl[ct], 0, 0, 0);
            accr[ct] = __builtin_amdgcn_mfma_f32_16x16x32_bf16(af, br, accr[ct], 0, 0, 0);
        }
    }

#pragma unroll
    for (int r = 0; r < 4; ++r) {
        const int orow = row0 + quad * 4 + r;
        if (orow < N_NODES) {
#pragma unroll
            for (int ct = 0; ct < 8; ++ct) {
                const int col = ct * 16 + m;
                p1f[(size_t)orow * HID_C + col] = f2fp8(accl[ct][r]);
                t1b[(size_t)orow * HID_C + col] = f2bf(accr[ct][r]);
            }
        }
    }
}

// ---------------------------------------------------------------------------
// K1: mm1 (blocks 0..781) | bucket scatter (blocks 782..1172).
// Scatter: int4 edge loads; LDS hist -> claim run per bucket -> packed words.
// ---------------------------------------------------------------------------
__global__ __launch_bounds__(256) void k1_kernel(
    const float* __restrict__ x, const ushort_t* __restrict__ wpack,
    uchar_t* __restrict__ p1f, ushort_t* __restrict__ t1b,
    const int* __restrict__ src, const int* __restrict__ dst,
    int* gcur, int* __restrict__ ebuf)
{
    __shared__ int lh[256], gbase[256], lcur[256];
    const int b = blockIdx.x;
    if (b < MM1_BLKS) {
        mm1_body(b, x, wpack, p1f, t1b);
        return;
    }
    const int blk = b - MM1_BLKS;
    const int t = threadIdx.x;
    lh[t] = 0;
    __syncthreads();
    const int e0 = blk * EPB + t * 8;        // N_EDGES % 8 == 0 -> chunk all-or-nothing
    int v8[8], b8[8];
    if (e0 < N_EDGES) {
        const int4 sa = *(const int4*)&src[e0];
        const int4 sb = *(const int4*)&src[e0 + 4];
        const int4 da = *(const int4*)&dst[e0];
        const int4 db = *(const int4*)&dst[e0 + 4];
        const int s8a[8] = {sa.x, sa.y, sa.z, sa.w, sb.x, sb.y, sb.z, sb.w};
        const int d8a[8] = {da.x, da.y, da.z, da.w, db.x, db.y, db.z, db.w};
#pragma unroll
        for (int j = 0; j < 8; ++j) {
            b8[j] = d8a[j] >> 8;
            v8[j] = (s8a[j] << 8) | (d8a[j] & 255);
            atomicAdd(&lh[b8[j]], 1);
        }
    } else {
#pragma unroll
        for (int j = 0; j < 8; ++j) b8[j] = -1;
    }
    __syncthreads();
    if (t < NBUCK) {
        const int run = lh[t];
        gbase[t] = (run > 0) ? atomicAdd(&gcur[t], run) : 0;
        lcur[t] = 0;
    }
    __syncthreads();
#pragma unroll
    for (int j = 0; j < 8; ++j) {
        const int bk = b8[j];
        if (bk >= 0) {
            const int p = atomicAdd(&lcur[bk], 1);
            ebuf[bk * BCAP + gbase[bk] + p] = v8[j];
        }
    }
}

// ---------------------------------------------------------------------------
// l2f: fused fill + agg1 + mm2. One block per QUARTER-bucket (64 nodes).
// Phase 0: scan own bucket's ebuf run; LDS hist+scan over own 64 nodes;
//          build LDS csr (own quarter only); stream csr/cnt/row_ptr to global
//          (fixed QCAP region per quarter) for agg2.
// Phase A: 16-lane groups pop nodes from LDS pool; gather-mean fp8 p1 rows
//          via LDS csr; h = relu(mean + b1 + t1) -> LDS bf16.
// Phase B: MFMA h @ W2l / h @ W2r from LDS -> p2f (fp8), t2b (bf16).
// ---------------------------------------------------------------------------
__global__ __launch_bounds__(256) void l2f_kernel(
    const int* __restrict__ ebuf, const int* __restrict__ gcur,
    int* __restrict__ cnt, int* __restrict__ row_ptr, int* __restrict__ csr_g,
    const uchar_t* __restrict__ p1f, const ushort_t* __restrict__ t1b,
    const float* __restrict__ b1,
    const ushort_t* __restrict__ wpack,
    uchar_t* __restrict__ p2f, ushort_t* __restrict__ t2b)
{
    __shared__ ushort_t hs[64 * HS_STRIDE];
    __shared__ int csr_lds[QCAP];
    __shared__ int lh[64], lstart[64], lcur2[64];
    __shared__ int pool;

    const int blk    = blockIdx.x;          // quarter index: bucket*4 + q
    const int bucket = blk >> 2;
    const int q      = blk & 3;
    const int tid    = threadIdx.x;

    if (tid == 0) pool = 0;
    if (tid < 64) lh[tid] = 0;
    __syncthreads();

    // ---- Phase 0: fill own quarter's csr from bucket's ebuf run ----
    const int eb0 = bucket * BCAP;
    const int nb  = gcur[bucket];
    for (int i = tid; i < nb; i += 256) {
        const int d = ebuf[eb0 + i] & 255;
        if ((d >> 6) == q) atomicAdd(&lh[d & 63], 1);
    }
    __syncthreads();
    // 64-wide Hillis-Steele inclusive scan in loff-space (reuse lcur2 as scratch)
    int scanv = 0;
    if (tid < 64) scanv = lh[tid];
    if (tid < 64) lcur2[tid] = scanv;
    __syncthreads();
#pragma unroll
    for (int off = 1; off < 64; off <<= 1) {
        int add = 0;
        if (tid < 64 && tid >= off) add = lcur2[tid - off];
        __syncthreads();
        if (tid < 64) lcur2[tid] += add;
        __syncthreads();
    }
    if (tid < 64) {
        const int ex = lcur2[tid] - scanv;       // exclusive offset
        lstart[tid] = ex;
        const int node = blk * 64 + tid;
        if (node < N_NODES) { cnt[node] = scanv; row_ptr[node] = blk * QCAP + ex; }
    }
    __syncthreads();
    if (tid < 64) lcur2[tid] = lstart[tid];      // running cursors
    __syncthreads();
    for (int i = tid; i < nb; i += 256) {
        const int v = ebuf[eb0 + i];
        const int d = v & 255;
        if ((d >> 6) == q) {
            const int p = atomicAdd(&lcur2[d & 63], 1);
            if (p < QCAP) csr_lds[p] = v >> 8;
        }
    }
    __syncthreads();
    // stream csr to global (coalesced) for agg2
    {
        const int tot = (tid < 64) ? 0 : 0;  (void)tot;
        const int total = lcur2[63] > QCAP ? QCAP : lcur2[63];
        for (int i = tid; i < total; i += 256) csr_g[blk * QCAP + i] = csr_lds[i];
    }
    __syncthreads();

    // ---- Phase A: gather-mean + h into LDS (dynamic node pool) ----
    const int c8 = tid & 15;                     // channels 8*c8 .. 8*c8+7
    const int gb = (tid & 63) & 48;              // group leader lane in wave
    const uint2* p1v = (const uint2*)p1f;        // row stride 16 uint2

    while (true) {
        int nl = 0;
        if (c8 == 0) nl = atomicAdd(&pool, 1);
        nl = __shfl(nl, gb, 64);
        if (nl >= 64) break;
        const int node = blk * 64 + nl;
        uint4 o = make_uint4(0u, 0u, 0u, 0u);
        if (node < N_NODES) {
            const int start = lstart[nl];
            const int degi  = lh[nl];
            float a0=0,a1=0,a2=0,a3=0,a4=0,a5=0,a6=0,a7=0;
            int e = 0;
            for (; e + 3 < degi; e += 4) {
                const int s0 = csr_lds[start + e];
                const int s1 = csr_lds[start + e + 1];
                const int s2 = csr_lds[start + e + 2];
                const int s3 = csr_lds[start + e + 3];
                const uint2 v0 = p1v[(size_t)s0 * 16 + c8];
                const uint2 v1 = p1v[(size_t)s1 * 16 + c8];
                const uint2 v2 = p1v[(size_t)s2 * 16 + c8];
                const uint2 v3 = p1v[(size_t)s3 * 16 + c8];
#pragma unroll
                for (int qq = 0; qq < 4; ++qq) {
                    const uint2 v = (qq == 0) ? v0 : (qq == 1) ? v1 : (qq == 2) ? v2 : v3;
                    const f32x2 lx = __builtin_amdgcn_cvt_pk_f32_fp8((int)v.x, false);
                    const f32x2 hx = __builtin_amdgcn_cvt_pk_f32_fp8((int)v.x, true);
                    const f32x2 ly = __builtin_amdgcn_cvt_pk_f32_fp8((int)v.y, false);
                    const f32x2 hy = __builtin_amdgcn_cvt_pk_f32_fp8((int)v.y, true);
                    a0 += lx.x; a1 += lx.y; a2 += hx.x; a3 += hx.y;
                    a4 += ly.x; a5 += ly.y; a6 += hy.x; a7 += hy.y;
                }
            }
            for (; e < degi; ++e) {
                const uint2 v = p1v[(size_t)csr_lds[start + e] * 16 + c8];
                const f32x2 lx = __builtin_amdgcn_cvt_pk_f32_fp8((int)v.x, false);
                const f32x2 hx = __builtin_amdgcn_cvt_pk_f32_fp8((int)v.x, true);
                const f32x2 ly = __builtin_amdgcn_cvt_pk_f32_fp8((int)v.y, false);
                const f32x2 hy = __builtin_amdgcn_cvt_pk_f32_fp8((int)v.y, true);
                a0 += lx.x; a1 += lx.y; a2 += hx.x; a3 += hx.y;
                a4 += ly.x; a5 += ly.y; a6 += hy.x; a7 += hy.y;
            }
            const float inv = 1.0f / fmaxf((float)degi, 1.0f);
            const size_t i = (size_t)node * HID_C + c8 * 8;
            const uint4 tv = *(const uint4*)(t1b + i);
            const float4 bL = *(const float4*)(b1 + c8 * 8);
            const float4 bH = *(const float4*)(b1 + c8 * 8 + 4);
            const float r0 = fmaxf(fmaf(a0, inv, bL.x + bflo(tv.x)), 0.0f);
            const float r1 = fmaxf(fmaf(a1, inv, bL.y + bfhi(tv.x)), 0.0f);
            const float r2 = fmaxf(fmaf(a2, inv, bL.z + bflo(tv.y)), 0.0f);
            const float r3 = fmaxf(fmaf(a3, inv, bL.w + bfhi(tv.y)), 0.0f);
            const float r4 = fmaxf(fmaf(a4, inv, bH.x + bflo(tv.z)), 0.0f);
            const float r5 = fmaxf(fmaf(a5, inv, bH.y + bfhi(tv.z)), 0.0f);
            const float r6 = fmaxf(fmaf(a6, inv, bH.z + bflo(tv.w)), 0.0f);
            const float r7 = fmaxf(fmaf(a7, inv, bH.w + bfhi(tv.w)), 0.0f);
            o.x = (uint_t)f2bf(r0) | ((uint_t)f2bf(r1) << 16);
            o.y = (uint_t)f2bf(r2) | ((uint_t)f2bf(r3) << 16);
            o.z = (uint_t)f2bf(r4) | ((uint_t)f2bf(r5) << 16);
            o.w = (uint_t)f2bf(r6) | ((uint_t)f2bf(r7) << 16);
        }
        *(uint4*)&hs[nl * HS_STRIDE + c8 * 8] = o;
    }
    __syncthreads();

    // ---- Phase B: MFMA. Wave wv owns rows wv*16..wv*16+15. ----
    const int wv   = tid >> 6;
    const int lane = tid & 63;
    const int quad = lane >> 4;
    const int m    = lane & 15;
    const int row0 = blk * 64 + wv * 16;

    const bf16x8* Bl = (const bf16x8*)(wpack + 32768);
    const bf16x8* Br = (const bf16x8*)(wpack + 40960);

    f32x4 accl[4], accr[4];
#pragma unroll
    for (int ct = 0; ct < 4; ++ct) { accl[ct] = (f32x4)(0.0f); accr[ct] = (f32x4)(0.0f); }

#pragma unroll
    for (int kt = 0; kt < 4; ++kt) {
        const bf16x8 af = *(const bf16x8*)&hs[(wv * 16 + m) * HS_STRIDE + kt * 32 + quad * 8];
#pragma unroll
        for (int ct = 0; ct < 4; ++ct) {
            const bf16x8 bl = Bl[(ct * 4 + kt) * 64 + lane];
            const bf16x8 br = Br[(ct * 4 + kt) * 64 + lane];
            accl[ct] = __builtin_amdgcn_mfma_f32_16x16x32_bf16(af, bl, accl[ct], 0, 0, 0);
            accr[ct] = __builtin_amdgcn_mfma_f32_16x16x32_bf16(af, br, accr[ct], 0, 0, 0);
        }
    }

#pragma unroll
    for (int r = 0; r < 4; ++r) {
        const int orow = row0 + quad * 4 + r;
        if (orow < N_NODES) {
#pragma unroll
            for (int ct = 0; ct < 4; ++ct) {
                const int col = ct * 16 + m;
                p2f[(size_t)orow * OUT_C + col] = f2fp8(accl[ct][r]);
                t2b[(size_t)orow * OUT_C + col] = f2bf(accr[ct][r]);
            }
        }
    }
}

// ---------------------------------------------------------------------------
// agg2: 64 nodes/block, 8 lanes/node (fp8 rows = 64B = 8 x uint2).
// out = mean(p2[src]) + b2 + t2.
// ---------------------------------------------------------------------------
__global__ __launch_bounds__(256) void agg2_kernel(
    const uchar_t* __restrict__ p2f, const ushort_t* __restrict__ t2b,
    const float* __restrict__ b2, const int* __restrict__ row_ptr,
    const int* __restrict__ cnt, const int* __restrict__ csr,
    float* __restrict__ out)
{
    const int c8  = threadIdx.x & 7;           // channels 8*c8 .. 8*c8+7
    const int grp = threadIdx.x >> 3;          // 0..31
    const uint2* p2v = (const uint2*)p2f;      // row stride 8 uint2

#pragma unroll
    for (int p = 0; p < 2; ++p) {
        const int node = blockIdx.x * 64 + p * 32 + grp;
        if (node >= N_NODES) continue;
        const int start = row_ptr[node];
        const int degi  = cnt[node];
        float a0=0,a1=0,a2=0,a3=0,a4=0,a5=0,a6=0,a7=0;
        int e = 0;
        for (; e + 3 < degi; e += 4) {
            const int s0 = csr[start + e];
            const int s1 = csr[start + e + 1];
            const int s2 = csr[start + e + 2];
            const int s3 = csr[start + e + 3];
            const uint2 v0 = p2v[(size_t)s0 * 8 + c8];
            const uint2 v1 = p2v[(size_t)s1 * 8 + c8];
            const uint2 v2 = p2v[(size_t)s2 * 8 + c8];
            const uint2 v3 = p2v[(size_t)s3 * 8 + c8];
#pragma unroll
            for (int q = 0; q < 4; ++q) {
                const uint2 v = (q == 0) ? v0 : (q == 1) ? v1 : (q == 2) ? v2 : v3;
                const f32x2 lx = __builtin_amdgcn_cvt_pk_f32_fp8((int)v.x, false);
                const f32x2 hx = __builtin_amdgcn_cvt_pk_f32_fp8((int)v.x, true);
                const f32x2 ly = __builtin_amdgcn_cvt_pk_f32_fp8((int)v.y, false);
                const f32x2 hy = __builtin_amdgcn_cvt_pk_f32_fp8((int)v.y, true);
                a0 += lx.x; a1 += lx.y; a2 += hx.x; a3 += hx.y;
                a4 += ly.x; a5 += ly.y; a6 += hy.x; a7 += hy.y;
            }
        }
        for (; e < degi; ++e) {
            const uint2 v = p2v[(size_t)csr[start + e] * 8 + c8];
            const f32x2 lx = __builtin_amdgcn_cvt_pk_f32_fp8((int)v.x, false);
            const f32x2 hx = __builtin_amdgcn_cvt_pk_f32_fp8((int)v.x, true);
            const f32x2 ly = __builtin_amdgcn_cvt_pk_f32_fp8((int)v.y, false);
            const f32x2 hy = __builtin_amdgcn_cvt_pk_f32_fp8((int)v.y, true);
            a0 += lx.x; a1 += lx.y; a2 += hx.x; a3 += hx.y;
            a4 += ly.x; a5 += ly.y; a6 += hy.x; a7 += hy.y;
        }

        const float inv = 1.0f / fmaxf((float)degi, 1.0f);
        const size_t i = (size_t)node * OUT_C + c8 * 8;
        const uint4 tv = *(const uint4*)(t2b + i);
        const float4 bL = *(const float4*)(b2 + c8 * 8);
        const float4 bH = *(const float4*)(b2 + c8 * 8 + 4);
        float4 oL, oH;
        oL.x = fmaf(a0, inv, bL.x + bflo(tv.x));
        oL.y = fmaf(a1, inv, bL.y + bfhi(tv.x));
        oL.z = fmaf(a2, inv, bL.z + bflo(tv.y));
        oL.w = fmaf(a3, inv, bL.w + bfhi(tv.y));
        oH.x = fmaf(a4, inv, bH.x + bflo(tv.z));
        oH.y = fmaf(a5, inv, bH.y + bfhi(tv.z));
        oH.z = fmaf(a6, inv, bH.z + bflo(tv.w));
        oH.w = fmaf(a7, inv, bH.w + bfhi(tv.w));
        *(float4*)(out + i) = oL;
        *(float4*)(out + i + 4) = oH;
    }
}

extern "C" void kernel_launch(void* const* d_in, const int* in_sizes, int n_in,
                              void* d_out, int out_size, void* d_ws, size_t ws_size,
                              hipStream_t stream)
{
    const float* x   = (const float*)d_in[0];
    const int*   ei  = (const int*)d_in[1];
    const float* W1l = (const float*)d_in[2];
    const float* b1  = (const float*)d_in[3];
    const float* W1r = (const float*)d_in[4];
    const float* W2l = (const float*)d_in[5];
    const float* b2  = (const float*)d_in[6];
    const float* W2r = (const float*)d_in[7];
    float* out = (float*)d_out;

    const int* src = ei;
    const int* dst = ei + N_EDGES;

    const size_t NH = (size_t)N_NODES * HID_C;   // 6.4M
    const size_t NO = (size_t)N_NODES * OUT_C;   // 3.2M
    const size_t EB = (size_t)NBUCK * BCAP;      // 1.204M slots
    const size_t CB = (size_t)L2F_BLKS * QCAP;   // 1.204M csr slots

    // Workspace layout (8B-aligned first, bytes last).
    char* ws = (char*)d_ws;
    ushort_t* t1b   = (ushort_t*)ws;                   ws += NH * sizeof(ushort_t);
    ushort_t* t2b   = (ushort_t*)ws;                   ws += NO * sizeof(ushort_t);
    ushort_t* wpack = (ushort_t*)ws;                   ws += 49152 * sizeof(ushort_t);
    int* ebuf    = (int*)ws;                           ws += EB * sizeof(int);
    int* csr     = (int*)ws;                           ws += CB * sizeof(int);
    int* cnt     = (int*)ws;                           ws += N_NODES * sizeof(int);
    int* row_ptr = (int*)ws;                           ws += N_NODES * sizeof(int);
    int* gcur    = (int*)ws;                           ws += NBUCK * sizeof(int);
    uchar_t* p1f = (uchar_t*)ws;                       ws += NH * sizeof(uchar_t);
    uchar_t* p2f = (uchar_t*)ws;                       ws += NO * sizeof(uchar_t);

    const size_t need = (size_t)(ws - (char*)d_ws);
    if (ws_size < need) return;

    // K0: pack weights | zero bucket cursors        (input-only)
    k0_kernel<<<PACK_BLKS + 1, 256, 0, stream>>>(W1l, W1r, W2l, W2r, wpack, gcur);
    // K1: mm1 | bucket scatter                      (reads only K0 outputs/inputs)
    k1_kernel<<<MM1_BLKS + EBLKS, 256, 0, stream>>>(
        x, wpack, p1f, t1b, src, dst, gcur, ebuf);
    // Fused fill + agg1 + mm2 (quarter-bucket blocks; csr built in LDS)
    l2f_kernel<<<L2F_BLKS, 256, 0, stream>>>(
        ebuf, gcur, cnt, row_ptr, csr, p1f, t1b, b1, wpack, p2f, t2b);
    // Final aggregation
    agg2_kernel<<<MM1_BLKS, 256, 0, stream>>>(
        p2f, t2b, b2, row_ptr, cnt, csr, out);
}

// Round 12
// 162.736 us; speedup vs baseline: 1.3519x; 1.0120x over previous
//
#include <hip/hip_runtime.h>

#define N_NODES 50000
#define N_EDGES 800000
#define IN_C    128
#define HID_C   128
#define OUT_C   64
#define NBUCK   196                         // ceil(50000/256) buckets of 256 nodes
#define BCAP    6144                        // fixed slots/bucket (mean 4082 -> 32 sigma headroom)
#define QCAP    1536                        // fixed csr slots per quarter (mean 1024, 16 sigma)
#define EPB     2048                        // edges per scatter block
#define EBLKS   ((N_EDGES + EPB - 1) / EPB) // 391
#define PACK_BLKS 192
#define MM1_BLKS  ((N_NODES + 63) / 64)     // 782
#define L2F_BLKS  (NBUCK * 4)               // 784 quarter-bucket blocks
#define HS_STRIDE 136                       // 128 ushorts + 8 pad -> 272B rows

typedef unsigned short ushort_t;
typedef unsigned int   uint_t;
typedef unsigned char  uchar_t;
typedef __attribute__((ext_vector_type(8))) short bf16x8;
typedef __attribute__((ext_vector_type(4))) float f32x4;
typedef __attribute__((ext_vector_type(2))) float f32x2;

__device__ inline ushort_t f2bf(float f) {
    uint_t u = __float_as_uint(f);
    uint_t r = (u + 0x7fffu + ((u >> 16) & 1u)) >> 16;
    return (ushort_t)r;
}
__device__ inline float bflo(uint_t v) { return __uint_as_float(v << 16); }
__device__ inline float bfhi(uint_t v) { return __uint_as_float(v & 0xffff0000u); }
__device__ inline uchar_t f2fp8(float v) {
    return (uchar_t)(__builtin_amdgcn_cvt_pk_fp8_f32(v, v, 0, false) & 0xff);
}

// ---------------------------------------------------------------------------
// Weight pre-pack into B-fragment order for mfma_f32_16x16x32_bf16.
// ---------------------------------------------------------------------------
__device__ inline void pack_one(const float* W, ushort_t* Wp, int K, int N, int idx) {
    const int j  = idx & 7;
    const int L  = (idx >> 3) & 63;
    const int t  = idx >> 9;
    const int KT = K / 32;
    const int kt = t % KT;
    const int ct = t / KT;
    const int k  = kt * 32 + (L >> 4) * 8 + j;
    const int n  = ct * 16 + (L & 15);
    Wp[idx] = f2bf(W[k * N + n]);
}

// ---------------------------------------------------------------------------
// K0: pack weights (blocks 0..191) | zero bucket cursors (block 192).
// ---------------------------------------------------------------------------
__global__ __launch_bounds__(256) void k0_kernel(
    const float* __restrict__ W1l, const float* __restrict__ W1r,
    const float* __restrict__ W2l, const float* __restrict__ W2r,
    ushort_t* __restrict__ wpack, int* __restrict__ gcur)
{
    const int b = blockIdx.x;
    if (b < PACK_BLKS) {
        const int tid = b * 256 + threadIdx.x;
        if (tid < 16384)      pack_one(W1l, wpack,          IN_C,  HID_C, tid);
        else if (tid < 32768) pack_one(W1r, wpack + 16384,  IN_C,  HID_C, tid - 16384);
        else if (tid < 40960) pack_one(W2l, wpack + 32768,  HID_C, OUT_C, tid - 32768);
        else if (tid < 49152) pack_one(W2r, wpack + 40960,  HID_C, OUT_C, tid - 40960);
    } else {
        if (threadIdx.x < NBUCK) gcur[threadIdx.x] = 0;
    }
}

// ---------------------------------------------------------------------------
// mm1 body: p1f = fp8(x @ W1l), t1b = bf16(x @ W1r). wpack from K0.
// ---------------------------------------------------------------------------
__device__ inline void mm1_body(int bid, const float* __restrict__ x,
                                const ushort_t* __restrict__ wpack,
                                uchar_t* __restrict__ p1f, ushort_t* __restrict__ t1b)
{
    const int wave = threadIdx.x >> 6;
    const int lane = threadIdx.x & 63;
    const int quad = lane >> 4;
    const int m    = lane & 15;
    const int row0 = bid * 64 + wave * 16;
    const int arow = min(row0 + m, N_NODES - 1);

    const bf16x8* Bl = (const bf16x8*)(wpack);
    const bf16x8* Br = (const bf16x8*)(wpack + 16384);

    f32x4 accl[8], accr[8];
#pragma unroll
    for (int ct = 0; ct < 8; ++ct) { accl[ct] = (f32x4)(0.0f); accr[ct] = (f32x4)(0.0f); }

#pragma unroll
    for (int kt = 0; kt < 4; ++kt) {
        const float* xp = x + (size_t)arow * IN_C + kt * 32 + quad * 8;
        const float4 a0 = *(const float4*)(xp);
        const float4 a1 = *(const float4*)(xp + 4);
        bf16x8 af;
        af[0] = (short)f2bf(a0.x); af[1] = (short)f2bf(a0.y);
        af[2] = (short)f2bf(a0.z); af[3] = (short)f2bf(a0.w);
        af[4] = (short)f2bf(a1.x); af[5] = (short)f2bf(a1.y);
        af[6] = (short)f2bf(a1.z); af[7] = (short)f2bf(a1.w);
#pragma unroll
        for (int ct = 0; ct < 8; ++ct) {
            const bf16x8 bl = Bl[(ct * 4 + kt) * 64 + lane];
            const bf16x8 br = Br[(ct * 4 + kt) * 64 + lane];
            accl[ct] = __builtin_amdgcn_mfma_f32_16x16x32_bf16(af, bl, accl[ct], 0, 0, 0);
            accr[ct] = __builtin_amdgcn_mfma_f32_16x16x32_bf16(af, br, accr[ct], 0, 0, 0);
        }
    }

#pragma unroll
    for (int r = 0; r < 4; ++r) {
        const int orow = row0 + quad * 4 + r;
        if (orow < N_NODES) {
#pragma unroll
            for (int ct = 0; ct < 8; ++ct) {
                const int col = ct * 16 + m;
                p1f[(size_t)orow * HID_C + col] = f2fp8(accl[ct][r]);
                t1b[(size_t)orow * HID_C + col] = f2bf(accr[ct][r]);
            }
        }
    }
}

// ---------------------------------------------------------------------------
// K1: mm1 (blocks 0..781) | bucket scatter (blocks 782..1172).
// Scatter: int4 edge loads; LDS hist -> claim run per bucket -> packed words.
// ---------------------------------------------------------------------------
__global__ __launch_bounds__(256) void k1_kernel(
    const float* __restrict__ x, const ushort_t* __restrict__ wpack,
    uchar_t* __restrict__ p1f, ushort_t* __restrict__ t1b,
    const int* __restrict__ src, const int* __restrict__ dst,
    int* gcur, int* __restrict__ ebuf)
{
    __shared__ int lh[256], gbase[256], lcur[256];
    const int b = blockIdx.x;
    if (b < MM1_BLKS) {
        mm1_body(b, x, wpack, p1f, t1b);
        return;
    }
    const int blk = b - MM1_BLKS;
    const int t = threadIdx.x;
    lh[t] = 0;
    __syncthreads();
    const int e0 = blk * EPB + t * 8;        // N_EDGES % 8 == 0 -> chunk all-or-nothing
    int v8[8], b8[8];
    if (e0 < N_EDGES) {
        const int4 sa = *(const int4*)&src[e0];
        const int4 sb = *(const int4*)&src[e0 + 4];
        const int4 da = *(const int4*)&dst[e0];
        const int4 db = *(const int4*)&dst[e0 + 4];
        const int s8a[8] = {sa.x, sa.y, sa.z, sa.w, sb.x, sb.y, sb.z, sb.w};
        const int d8a[8] = {da.x, da.y, da.z, da.w, db.x, db.y, db.z, db.w};
#pragma unroll
        for (int j = 0; j < 8; ++j) {
            b8[j] = d8a[j] >> 8;
            v8[j] = (s8a[j] << 8) | (d8a[j] & 255);
            atomicAdd(&lh[b8[j]], 1);
        }
    } else {
#pragma unroll
        for (int j = 0; j < 8; ++j) b8[j] = -1;
    }
    __syncthreads();
    if (t < NBUCK) {
        const int run = lh[t];
        gbase[t] = (run > 0) ? atomicAdd(&gcur[t], run) : 0;
        lcur[t] = 0;
    }
    __syncthreads();
#pragma unroll
    for (int j = 0; j < 8; ++j) {
        const int bk = b8[j];
        if (bk >= 0) {
            const int p = atomicAdd(&lcur[bk], 1);
            ebuf[bk * BCAP + gbase[bk] + p] = v8[j];
        }
    }
}

// ---------------------------------------------------------------------------
// l2f: fused fill + agg1 + mm2. One block per QUARTER-bucket (64 nodes).
// Phase 0: scan own bucket's ebuf run; LDS hist+scan over own 64 nodes;
//          build LDS csr; stream csr/cnt/row_ptr to global for agg2.
// Phase A: 16-lane groups pop nodes from LDS pool; gather-mean fp8 p1 rows
//          via LDS csr; h = relu(mean + b1 + t1) -> LDS bf16.
// Phase B: MFMA h @ W2l / h @ W2r from LDS -> p2f (fp8), t2b (bf16).
// __launch_bounds__(256,4): cap VGPR at 128 -> >=4 blocks/CU for gather
// latency hiding (LDS 24.3 KB allows 6).
// ---------------------------------------------------------------------------
__global__ __launch_bounds__(256, 4) void l2f_kernel(
    const int* __restrict__ ebuf, const int* __restrict__ gcur,
    int* __restrict__ cnt, int* __restrict__ row_ptr, int* __restrict__ csr_g,
    const uchar_t* __restrict__ p1f, const ushort_t* __restrict__ t1b,
    const float* __restrict__ b1,
    const ushort_t* __restrict__ wpack,
    uchar_t* __restrict__ p2f, ushort_t* __restrict__ t2b)
{
    __shared__ ushort_t hs[64 * HS_STRIDE];
    __shared__ int csr_lds[QCAP];
    __shared__ int lh[64], lstart[64], lcur2[64];
    __shared__ int pool;

    const int blk    = blockIdx.x;          // quarter index: bucket*4 + q
    const int bucket = blk >> 2;
    const int q      = blk & 3;
    const int tid    = threadIdx.x;

    if (tid == 0) pool = 0;
    if (tid < 64) lh[tid] = 0;
    __syncthreads();

    // ---- Phase 0: fill own quarter's csr from bucket's ebuf run ----
    const int eb0 = bucket * BCAP;
    const int nb  = gcur[bucket];
    for (int i = tid; i < nb; i += 256) {
        const int d = ebuf[eb0 + i] & 255;
        if ((d >> 6) == q) atomicAdd(&lh[d & 63], 1);
    }
    __syncthreads();
    int scanv = 0;
    if (tid < 64) scanv = lh[tid];
    if (tid < 64) lcur2[tid] = scanv;
    __syncthreads();
#pragma unroll
    for (int off = 1; off < 64; off <<= 1) {
        int add = 0;
        if (tid < 64 && tid >= off) add = lcur2[tid - off];
        __syncthreads();
        if (tid < 64) lcur2[tid] += add;
        __syncthreads();
    }
    if (tid < 64) {
        const int ex = lcur2[tid] - scanv;       // exclusive offset
        lstart[tid] = ex;
        const int node = blk * 64 + tid;
        if (node < N_NODES) { cnt[node] = scanv; row_ptr[node] = blk * QCAP + ex; }
    }
    __syncthreads();
    if (tid < 64) lcur2[tid] = lstart[tid];      // running cursors
    __syncthreads();
    for (int i = tid; i < nb; i += 256) {
        const int v = ebuf[eb0 + i];
        const int d = v & 255;
        if ((d >> 6) == q) {
            const int p = atomicAdd(&lcur2[d & 63], 1);
            if (p < QCAP) csr_lds[p] = v >> 8;
        }
    }
    __syncthreads();
    // stream csr to global (coalesced) for agg2
    {
        const int total = lcur2[63] > QCAP ? QCAP : lcur2[63];
        for (int i = tid; i < total; i += 256) csr_g[blk * QCAP + i] = csr_lds[i];
    }
    __syncthreads();

    // ---- Phase A: gather-mean + h into LDS (dynamic node pool) ----
    const int c8 = tid & 15;                     // channels 8*c8 .. 8*c8+7
    const int gb = (tid & 63) & 48;              // group leader lane in wave
    const uint2* p1v = (const uint2*)p1f;        // row stride 16 uint2

    while (true) {
        int nl = 0;
        if (c8 == 0) nl = atomicAdd(&pool, 1);
        nl = __shfl(nl, gb, 64);
        if (nl >= 64) break;
        const int node = blk * 64 + nl;
        uint4 o = make_uint4(0u, 0u, 0u, 0u);
        if (node < N_NODES) {
            const int start = lstart[nl];
            const int degi  = lh[nl];
            float a0=0,a1=0,a2=0,a3=0,a4=0,a5=0,a6=0,a7=0;
            int e = 0;
            for (; e + 3 < degi; e += 4) {
                const int s0 = csr_lds[start + e];
                const int s1 = csr_lds[start + e + 1];
                const int s2 = csr_lds[start + e + 2];
                const int s3 = csr_lds[start + e + 3];
                const uint2 v0 = p1v[(size_t)s0 * 16 + c8];
                const uint2 v1 = p1v[(size_t)s1 * 16 + c8];
                const uint2 v2 = p1v[(size_t)s2 * 16 + c8];
                const uint2 v3 = p1v[(size_t)s3 * 16 + c8];
#pragma unroll
                for (int qq = 0; qq < 4; ++qq) {
                    const uint2 v = (qq == 0) ? v0 : (qq == 1) ? v1 : (qq == 2) ? v2 : v3;
                    const f32x2 lx = __builtin_amdgcn_cvt_pk_f32_fp8((int)v.x, false);
                    const f32x2 hx = __builtin_amdgcn_cvt_pk_f32_fp8((int)v.x, true);
                    const f32x2 ly = __builtin_amdgcn_cvt_pk_f32_fp8((int)v.y, false);
                    const f32x2 hy = __builtin_amdgcn_cvt_pk_f32_fp8((int)v.y, true);
                    a0 += lx.x; a1 += lx.y; a2 += hx.x; a3 += hx.y;
                    a4 += ly.x; a5 += ly.y; a6 += hy.x; a7 += hy.y;
                }
            }
            for (; e < degi; ++e) {
                const uint2 v = p1v[(size_t)csr_lds[start + e] * 16 + c8];
                const f32x2 lx = __builtin_amdgcn_cvt_pk_f32_fp8((int)v.x, false);
                const f32x2 hx = __builtin_amdgcn_cvt_pk_f32_fp8((int)v.x, true);
                const f32x2 ly = __builtin_amdgcn_cvt_pk_f32_fp8((int)v.y, false);
                const f32x2 hy = __builtin_amdgcn_cvt_pk_f32_fp8((int)v.y, true);
                a0 += lx.x; a1 += lx.y; a2 += hx.x; a3 += hx.y;
                a4 += ly.x; a5 += ly.y; a6 += hy.x; a7 += hy.y;
            }
            const float inv = 1.0f / fmaxf((float)degi, 1.0f);
            const size_t i = (size_t)node * HID_C + c8 * 8;
            const uint4 tv = *(const uint4*)(t1b + i);
            const float4 bL = *(const float4*)(b1 + c8 * 8);
            const float4 bH = *(const float4*)(b1 + c8 * 8 + 4);
            const float r0 = fmaxf(fmaf(a0, inv, bL.x + bflo(tv.x)), 0.0f);
            const float r1 = fmaxf(fmaf(a1, inv, bL.y + bfhi(tv.x)), 0.0f);
            const float r2 = fmaxf(fmaf(a2, inv, bL.z + bflo(tv.y)), 0.0f);
            const float r3 = fmaxf(fmaf(a3, inv, bL.w + bfhi(tv.y)), 0.0f);
            const float r4 = fmaxf(fmaf(a4, inv, bH.x + bflo(tv.z)), 0.0f);
            const float r5 = fmaxf(fmaf(a5, inv, bH.y + bfhi(tv.z)), 0.0f);
            const float r6 = fmaxf(fmaf(a6, inv, bH.z + bflo(tv.w)), 0.0f);
            const float r7 = fmaxf(fmaf(a7, inv, bH.w + bfhi(tv.w)), 0.0f);
            o.x = (uint_t)f2bf(r0) | ((uint_t)f2bf(r1) << 16);
            o.y = (uint_t)f2bf(r2) | ((uint_t)f2bf(r3) << 16);
            o.z = (uint_t)f2bf(r4) | ((uint_t)f2bf(r5) << 16);
            o.w = (uint_t)f2bf(r6) | ((uint_t)f2bf(r7) << 16);
        }
        *(uint4*)&hs[nl * HS_STRIDE + c8 * 8] = o;
    }
    __syncthreads();

    // ---- Phase B: MFMA. Wave wv owns rows wv*16..wv*16+15. ----
    const int wv   = tid >> 6;
    const int lane = tid & 63;
    const int quad = lane >> 4;
    const int m    = lane & 15;
    const int row0 = blk * 64 + wv * 16;

    const bf16x8* Bl = (const bf16x8*)(wpack + 32768);
    const bf16x8* Br = (const bf16x8*)(wpack + 40960);

    f32x4 accl[4], accr[4];
#pragma unroll
    for (int ct = 0; ct < 4; ++ct) { accl[ct] = (f32x4)(0.0f); accr[ct] = (f32x4)(0.0f); }

#pragma unroll
    for (int kt = 0; kt < 4; ++kt) {
        const bf16x8 af = *(const bf16x8*)&hs[(wv * 16 + m) * HS_STRIDE + kt * 32 + quad * 8];
#pragma unroll
        for (int ct = 0; ct < 4; ++ct) {
            const bf16x8 bl = Bl[(ct * 4 + kt) * 64 + lane];
            const bf16x8 br = Br[(ct * 4 + kt) * 64 + lane];
            accl[ct] = __builtin_amdgcn_mfma_f32_16x16x32_bf16(af, bl, accl[ct], 0, 0, 0);
            accr[ct] = __builtin_amdgcn_mfma_f32_16x16x32_bf16(af, br, accr[ct], 0, 0, 0);
        }
    }

#pragma unroll
    for (int r = 0; r < 4; ++r) {
        const int orow = row0 + quad * 4 + r;
        if (orow < N_NODES) {
#pragma unroll
            for (int ct = 0; ct < 4; ++ct) {
                const int col = ct * 16 + m;
                p2f[(size_t)orow * OUT_C + col] = f2fp8(accl[ct][r]);
                t2b[(size_t)orow * OUT_C + col] = f2bf(accr[ct][r]);
            }
        }
    }
}

// ---------------------------------------------------------------------------
// agg2: 64 nodes/block, 8 lanes/node (fp8 rows = 64B = 8 x uint2).
// out = mean(p2[src]) + b2 + t2.
// ---------------------------------------------------------------------------
__global__ __launch_bounds__(256) void agg2_kernel(
    const uchar_t* __restrict__ p2f, const ushort_t* __restrict__ t2b,
    const float* __restrict__ b2, const int* __restrict__ row_ptr,
    const int* __restrict__ cnt, const int* __restrict__ csr,
    float* __restrict__ out)
{
    const int c8  = threadIdx.x & 7;           // channels 8*c8 .. 8*c8+7
    const int grp = threadIdx.x >> 3;          // 0..31
    const uint2* p2v = (const uint2*)p2f;      // row stride 8 uint2

#pragma unroll
    for (int p = 0; p < 2; ++p) {
        const int node = blockIdx.x * 64 + p * 32 + grp;
        if (node >= N_NODES) continue;
        const int start = row_ptr[node];
        const int degi  = cnt[node];
        float a0=0,a1=0,a2=0,a3=0,a4=0,a5=0,a6=0,a7=0;
        int e = 0;
        for (; e + 3 < degi; e += 4) {
            const int s0 = csr[start + e];
            const int s1 = csr[start + e + 1];
            const int s2 = csr[start + e + 2];
            const int s3 = csr[start + e + 3];
            const uint2 v0 = p2v[(size_t)s0 * 8 + c8];
            const uint2 v1 = p2v[(size_t)s1 * 8 + c8];
            const uint2 v2 = p2v[(size_t)s2 * 8 + c8];
            const uint2 v3 = p2v[(size_t)s3 * 8 + c8];
#pragma unroll
            for (int q = 0; q < 4; ++q) {
                const uint2 v = (q == 0) ? v0 : (q == 1) ? v1 : (q == 2) ? v2 : v3;
                const f32x2 lx = __builtin_amdgcn_cvt_pk_f32_fp8((int)v.x, false);
                const f32x2 hx = __builtin_amdgcn_cvt_pk_f32_fp8((int)v.x, true);
                const f32x2 ly = __builtin_amdgcn_cvt_pk_f32_fp8((int)v.y, false);
                const f32x2 hy = __builtin_amdgcn_cvt_pk_f32_fp8((int)v.y, true);
                a0 += lx.x; a1 += lx.y; a2 += hx.x; a3 += hx.y;
                a4 += ly.x; a5 += ly.y; a6 += hy.x; a7 += hy.y;
            }
        }
        for (; e < degi; ++e) {
            const uint2 v = p2v[(size_t)csr[start + e] * 8 + c8];
            const f32x2 lx = __builtin_amdgcn_cvt_pk_f32_fp8((int)v.x, false);
            const f32x2 hx = __builtin_amdgcn_cvt_pk_f32_fp8((int)v.x, true);
            const f32x2 ly = __builtin_amdgcn_cvt_pk_f32_fp8((int)v.y, false);
            const f32x2 hy = __builtin_amdgcn_cvt_pk_f32_fp8((int)v.y, true);
            a0 += lx.x; a1 += lx.y; a2 += hx.x; a3 += hx.y;
            a4 += ly.x; a5 += ly.y; a6 += hy.x; a7 += hy.y;
        }

        const float inv = 1.0f / fmaxf((float)degi, 1.0f);
        const size_t i = (size_t)node * OUT_C + c8 * 8;
        const uint4 tv = *(const uint4*)(t2b + i);
        const float4 bL = *(const float4*)(b2 + c8 * 8);
        const float4 bH = *(const float4*)(b2 + c8 * 8 + 4);
        float4 oL, oH;
        oL.x = fmaf(a0, inv, bL.x + bflo(tv.x));
        oL.y = fmaf(a1, inv, bL.y + bfhi(tv.x));
        oL.z = fmaf(a2, inv, bL.z + bflo(tv.y));
        oL.w = fmaf(a3, inv, bL.w + bfhi(tv.y));
        oH.x = fmaf(a4, inv, bH.x + bflo(tv.z));
        oH.y = fmaf(a5, inv, bH.y + bfhi(tv.z));
        oH.z = fmaf(a6, inv, bH.z + bflo(tv.w));
        oH.w = fmaf(a7, inv, bH.w + bfhi(tv.w));
        *(float4*)(out + i) = oL;
        *(float4*)(out + i + 4) = oH;
    }
}

extern "C" void kernel_launch(void* const* d_in, const int* in_sizes, int n_in,
                              void* d_out, int out_size, void* d_ws, size_t ws_size,
                              hipStream_t stream)
{
    const float* x   = (const float*)d_in[0];
    const int*   ei  = (const int*)d_in[1];
    const float* W1l = (const float*)d_in[2];
    const float* b1  = (const float*)d_in[3];
    const float* W1r = (const float*)d_in[4];
    const float* W2l = (const float*)d_in[5];
    const float* b2  = (const float*)d_in[6];
    const float* W2r = (const float*)d_in[7];
    float* out = (float*)d_out;

    const int* src = ei;
    const int* dst = ei + N_EDGES;

    const size_t NH = (size_t)N_NODES * HID_C;   // 6.4M
    const size_t NO = (size_t)N_NODES * OUT_C;   // 3.2M
    const size_t EB = (size_t)NBUCK * BCAP;      // 1.204M slots
    const size_t CB = (size_t)L2F_BLKS * QCAP;   // 1.204M csr slots

    // Workspace layout (8B-aligned first, bytes last).
    char* ws = (char*)d_ws;
    ushort_t* t1b   = (ushort_t*)ws;                   ws += NH * sizeof(ushort_t);
    ushort_t* t2b   = (ushort_t*)ws;                   ws += NO * sizeof(ushort_t);
    ushort_t* wpack = (ushort_t*)ws;                   ws += 49152 * sizeof(ushort_t);
    int* ebuf    = (int*)ws;                           ws += EB * sizeof(int);
    int* csr     = (int*)ws;                           ws += CB * sizeof(int);
    int* cnt     = (int*)ws;                           ws += N_NODES * sizeof(int);
    int* row_ptr = (int*)ws;                           ws += N_NODES * sizeof(int);
    int* gcur    = (int*)ws;                           ws += NBUCK * sizeof(int);
    uchar_t* p1f = (uchar_t*)ws;                       ws += NH * sizeof(uchar_t);
    uchar_t* p2f = (uchar_t*)ws;                       ws += NO * sizeof(uchar_t);

    const size_t need = (size_t)(ws - (char*)d_ws);
    if (ws_size < need) return;

    // K0: pack weights | zero bucket cursors        (input-only)
    k0_kernel<<<PACK_BLKS + 1, 256, 0, stream>>>(W1l, W1r, W2l, W2r, wpack, gcur);
    // K1: mm1 | bucket scatter                      (reads only K0 outputs/inputs)
    k1_kernel<<<MM1_BLKS + EBLKS, 256, 0, stream>>>(
        x, wpack, p1f, t1b, src, dst, gcur, ebuf);
    // Fused fill + agg1 + mm2 (quarter-bucket blocks; csr built in LDS)
    l2f_kernel<<<L2F_BLKS, 256, 0, stream>>>(
        ebuf, gcur, cnt, row_ptr, csr, p1f, t1b, b1, wpack, p2f, t2b);
    // Final aggregation
    agg2_kernel<<<MM1_BLKS, 256, 0, stream>>>(
        p2f, t2b, b2, row_ptr, cnt, csr, out);
}

// Round 13
// 160.809 us; speedup vs baseline: 1.3681x; 1.0120x over previous
//
#include <hip/hip_runtime.h>

#define N_NODES 50000
#define N_EDGES 800000
#define IN_C    128
#define HID_C   128
#define OUT_C   64
#define NBUCK   196                         // ceil(50000/256) buckets of 256 nodes
#define BCAP    6144                        // fixed slots/bucket (mean 4082 -> 32 sigma headroom)
#define QCAP    1536                        // fixed csr slots per quarter (mean 1024, 16 sigma)
#define EPB     2048                        // edges per scatter block
#define EBLKS   ((N_EDGES + EPB - 1) / EPB) // 391
#define PACK_BLKS 192
#define MM1_BLKS  ((N_NODES + 63) / 64)     // 782
#define L2F_BLKS  (NBUCK * 4)               // 784 quarter-bucket blocks
#define HS_STRIDE 136                       // 128 ushorts + 8 pad -> 272B rows

typedef unsigned short ushort_t;
typedef unsigned int   uint_t;
typedef unsigned char  uchar_t;
typedef __attribute__((ext_vector_type(8))) short bf16x8;
typedef __attribute__((ext_vector_type(4))) float f32x4;
typedef __attribute__((ext_vector_type(2))) float f32x2;

__device__ inline ushort_t f2bf(float f) {
    uint_t u = __float_as_uint(f);
    uint_t r = (u + 0x7fffu + ((u >> 16) & 1u)) >> 16;
    return (ushort_t)r;
}
__device__ inline float bflo(uint_t v) { return __uint_as_float(v << 16); }
__device__ inline float bfhi(uint_t v) { return __uint_as_float(v & 0xffff0000u); }
__device__ inline uchar_t f2fp8(float v) {
    return (uchar_t)(__builtin_amdgcn_cvt_pk_fp8_f32(v, v, 0, false) & 0xff);
}
// decode one dword = 4 fp8 -> acc[0..3]
__device__ inline void acc_fp8x4(float* a, uint_t d) {
    const f32x2 lo = __builtin_amdgcn_cvt_pk_f32_fp8((int)d, false);
    const f32x2 hi = __builtin_amdgcn_cvt_pk_f32_fp8((int)d, true);
    a[0] += lo.x; a[1] += lo.y; a[2] += hi.x; a[3] += hi.y;
}

// ---------------------------------------------------------------------------
// Weight pre-pack into B-fragment order for mfma_f32_16x16x32_bf16.
// ---------------------------------------------------------------------------
__device__ inline void pack_one(const float* W, ushort_t* Wp, int K, int N, int idx) {
    const int j  = idx & 7;
    const int L  = (idx >> 3) & 63;
    const int t  = idx >> 9;
    const int KT = K / 32;
    const int kt = t % KT;
    const int ct = t / KT;
    const int k  = kt * 32 + (L >> 4) * 8 + j;
    const int n  = ct * 16 + (L & 15);
    Wp[idx] = f2bf(W[k * N + n]);
}

// ---------------------------------------------------------------------------
// K0: pack weights (blocks 0..191) | zero bucket cursors (block 192).
// ---------------------------------------------------------------------------
__global__ __launch_bounds__(256) void k0_kernel(
    const float* __restrict__ W1l, const float* __restrict__ W1r,
    const float* __restrict__ W2l, const float* __restrict__ W2r,
    ushort_t* __restrict__ wpack, int* __restrict__ gcur)
{
    const int b = blockIdx.x;
    if (b < PACK_BLKS) {
        const int tid = b * 256 + threadIdx.x;
        if (tid < 16384)      pack_one(W1l, wpack,          IN_C,  HID_C, tid);
        else if (tid < 32768) pack_one(W1r, wpack + 16384,  IN_C,  HID_C, tid - 16384);
        else if (tid < 40960) pack_one(W2l, wpack + 32768,  HID_C, OUT_C, tid - 32768);
        else if (tid < 49152) pack_one(W2r, wpack + 40960,  HID_C, OUT_C, tid - 40960);
    } else {
        if (threadIdx.x < NBUCK) gcur[threadIdx.x] = 0;
    }
}

// ---------------------------------------------------------------------------
// mm1 body: p1f = fp8(x @ W1l), t1b = bf16(x @ W1r). wpack from K0.
// ---------------------------------------------------------------------------
__device__ inline void mm1_body(int bid, const float* __restrict__ x,
                                const ushort_t* __restrict__ wpack,
                                uchar_t* __restrict__ p1f, ushort_t* __restrict__ t1b)
{
    const int wave = threadIdx.x >> 6;
    const int lane = threadIdx.x & 63;
    const int quad = lane >> 4;
    const int m    = lane & 15;
    const int row0 = bid * 64 + wave * 16;
    const int arow = min(row0 + m, N_NODES - 1);

    const bf16x8* Bl = (const bf16x8*)(wpack);
    const bf16x8* Br = (const bf16x8*)(wpack + 16384);

    f32x4 accl[8], accr[8];
#pragma unroll
    for (int ct = 0; ct < 8; ++ct) { accl[ct] = (f32x4)(0.0f); accr[ct] = (f32x4)(0.0f); }

#pragma unroll
    for (int kt = 0; kt < 4; ++kt) {
        const float* xp = x + (size_t)arow * IN_C + kt * 32 + quad * 8;
        const float4 a0 = *(const float4*)(xp);
        const float4 a1 = *(const float4*)(xp + 4);
        bf16x8 af;
        af[0] = (short)f2bf(a0.x); af[1] = (short)f2bf(a0.y);
        af[2] = (short)f2bf(a0.z); af[3] = (short)f2bf(a0.w);
        af[4] = (short)f2bf(a1.x); af[5] = (short)f2bf(a1.y);
        af[6] = (short)f2bf(a1.z); af[7] = (short)f2bf(a1.w);
#pragma unroll
        for (int ct = 0; ct < 8; ++ct) {
            const bf16x8 bl = Bl[(ct * 4 + kt) * 64 + lane];
            const bf16x8 br = Br[(ct * 4 + kt) * 64 + lane];
            accl[ct] = __builtin_amdgcn_mfma_f32_16x16x32_bf16(af, bl, accl[ct], 0, 0, 0);
            accr[ct] = __builtin_amdgcn_mfma_f32_16x16x32_bf16(af, br, accr[ct], 0, 0, 0);
        }
    }

#pragma unroll
    for (int r = 0; r < 4; ++r) {
        const int orow = row0 + quad * 4 + r;
        if (orow < N_NODES) {
#pragma unroll
            for (int ct = 0; ct < 8; ++ct) {
                const int col = ct * 16 + m;
                p1f[(size_t)orow * HID_C + col] = f2fp8(accl[ct][r]);
                t1b[(size_t)orow * HID_C + col] = f2bf(accr[ct][r]);
            }
        }
    }
}

// ---------------------------------------------------------------------------
// K1: mm1 (blocks 0..781) | bucket scatter (blocks 782..1172).
// ---------------------------------------------------------------------------
__global__ __launch_bounds__(256) void k1_kernel(
    const float* __restrict__ x, const ushort_t* __restrict__ wpack,
    uchar_t* __restrict__ p1f, ushort_t* __restrict__ t1b,
    const int* __restrict__ src, const int* __restrict__ dst,
    int* gcur, int* __restrict__ ebuf)
{
    __shared__ int lh[256], gbase[256], lcur[256];
    const int b = blockIdx.x;
    if (b < MM1_BLKS) {
        mm1_body(b, x, wpack, p1f, t1b);
        return;
    }
    const int blk = b - MM1_BLKS;
    const int t = threadIdx.x;
    lh[t] = 0;
    __syncthreads();
    const int e0 = blk * EPB + t * 8;        // N_EDGES % 8 == 0 -> chunk all-or-nothing
    int v8[8], b8[8];
    if (e0 < N_EDGES) {
        const int4 sa = *(const int4*)&src[e0];
        const int4 sb = *(const int4*)&src[e0 + 4];
        const int4 da = *(const int4*)&dst[e0];
        const int4 db = *(const int4*)&dst[e0 + 4];
        const int s8a[8] = {sa.x, sa.y, sa.z, sa.w, sb.x, sb.y, sb.z, sb.w};
        const int d8a[8] = {da.x, da.y, da.z, da.w, db.x, db.y, db.z, db.w};
#pragma unroll
        for (int j = 0; j < 8; ++j) {
            b8[j] = d8a[j] >> 8;
            v8[j] = (s8a[j] << 8) | (d8a[j] & 255);
            atomicAdd(&lh[b8[j]], 1);
        }
    } else {
#pragma unroll
        for (int j = 0; j < 8; ++j) b8[j] = -1;
    }
    __syncthreads();
    if (t < NBUCK) {
        const int run = lh[t];
        gbase[t] = (run > 0) ? atomicAdd(&gcur[t], run) : 0;
        lcur[t] = 0;
    }
    __syncthreads();
#pragma unroll
    for (int j = 0; j < 8; ++j) {
        const int bk = b8[j];
        if (bk >= 0) {
            const int p = atomicAdd(&lcur[bk], 1);
            ebuf[bk * BCAP + gbase[bk] + p] = v8[j];
        }
    }
}

// ---------------------------------------------------------------------------
// l2f: fused fill + agg1 + mm2. One block per QUARTER-bucket (64 nodes).
// Phase A now: 8 lanes/node, uint4 (16 fp8 ch) loads -> one dwordx4 per lane
// covers the whole 128B row per 8-lane group.
// ---------------------------------------------------------------------------
__global__ __launch_bounds__(256, 4) void l2f_kernel(
    const int* __restrict__ ebuf, const int* __restrict__ gcur,
    int* __restrict__ cnt, int* __restrict__ row_ptr, int* __restrict__ csr_g,
    const uchar_t* __restrict__ p1f, const ushort_t* __restrict__ t1b,
    const float* __restrict__ b1,
    const ushort_t* __restrict__ wpack,
    uchar_t* __restrict__ p2f, ushort_t* __restrict__ t2b)
{
    __shared__ ushort_t hs[64 * HS_STRIDE];
    __shared__ int csr_lds[QCAP];
    __shared__ int lh[64], lstart[64], lcur2[64];
    __shared__ int pool;

    const int blk    = blockIdx.x;          // quarter index: bucket*4 + q
    const int bucket = blk >> 2;
    const int q      = blk & 3;
    const int tid    = threadIdx.x;

    if (tid == 0) pool = 0;
    if (tid < 64) lh[tid] = 0;
    __syncthreads();

    // ---- Phase 0: fill own quarter's csr from bucket's ebuf run ----
    const int eb0 = bucket * BCAP;
    const int nb  = gcur[bucket];
    for (int i = tid; i < nb; i += 256) {
        const int d = ebuf[eb0 + i] & 255;
        if ((d >> 6) == q) atomicAdd(&lh[d & 63], 1);
    }
    __syncthreads();
    int scanv = 0;
    if (tid < 64) scanv = lh[tid];
    if (tid < 64) lcur2[tid] = scanv;
    __syncthreads();
#pragma unroll
    for (int off = 1; off < 64; off <<= 1) {
        int add = 0;
        if (tid < 64 && tid >= off) add = lcur2[tid - off];
        __syncthreads();
        if (tid < 64) lcur2[tid] += add;
        __syncthreads();
    }
    if (tid < 64) {
        const int ex = lcur2[tid] - scanv;       // exclusive offset
        lstart[tid] = ex;
        const int node = blk * 64 + tid;
        if (node < N_NODES) { cnt[node] = scanv; row_ptr[node] = blk * QCAP + ex; }
    }
    __syncthreads();
    if (tid < 64) lcur2[tid] = lstart[tid];      // running cursors
    __syncthreads();
    for (int i = tid; i < nb; i += 256) {
        const int v = ebuf[eb0 + i];
        const int d = v & 255;
        if ((d >> 6) == q) {
            const int p = atomicAdd(&lcur2[d & 63], 1);
            if (p < QCAP) csr_lds[p] = v >> 8;
        }
    }
    __syncthreads();
    // stream csr to global (coalesced) for agg2
    {
        const int total = lcur2[63] > QCAP ? QCAP : lcur2[63];
        for (int i = tid; i < total; i += 256) csr_g[blk * QCAP + i] = csr_lds[i];
    }
    __syncthreads();

    // ---- Phase A: gather-mean + h into LDS (8 lanes/node, uint4 loads) ----
    const int c16 = tid & 7;                     // channels 16*c16 .. 16*c16+15
    const int gb  = (tid & 63) & 56;             // 8-lane group leader in wave
    const uint4* p1v = (const uint4*)p1f;        // row stride 8 uint4

    while (true) {
        int nl = 0;
        if (c16 == 0) nl = atomicAdd(&pool, 1);
        nl = __shfl(nl, gb, 64);
        if (nl >= 64) break;
        const int node = blk * 64 + nl;
        uint4 oL = make_uint4(0u, 0u, 0u, 0u);
        uint4 oH = make_uint4(0u, 0u, 0u, 0u);
        if (node < N_NODES) {
            const int start = lstart[nl];
            const int degi  = lh[nl];
            float a[16];
#pragma unroll
            for (int z = 0; z < 16; ++z) a[z] = 0.0f;
            int e = 0;
            for (; e + 3 < degi; e += 4) {
                const int s0 = csr_lds[start + e];
                const int s1 = csr_lds[start + e + 1];
                const int s2 = csr_lds[start + e + 2];
                const int s3 = csr_lds[start + e + 3];
                const uint4 v0 = p1v[(size_t)s0 * 8 + c16];
                const uint4 v1 = p1v[(size_t)s1 * 8 + c16];
                const uint4 v2 = p1v[(size_t)s2 * 8 + c16];
                const uint4 v3 = p1v[(size_t)s3 * 8 + c16];
#pragma unroll
                for (int qq = 0; qq < 4; ++qq) {
                    const uint4 v = (qq == 0) ? v0 : (qq == 1) ? v1 : (qq == 2) ? v2 : v3;
                    acc_fp8x4(a + 0,  v.x);
                    acc_fp8x4(a + 4,  v.y);
                    acc_fp8x4(a + 8,  v.z);
                    acc_fp8x4(a + 12, v.w);
                }
            }
            for (; e < degi; ++e) {
                const uint4 v = p1v[(size_t)csr_lds[start + e] * 8 + c16];
                acc_fp8x4(a + 0,  v.x);
                acc_fp8x4(a + 4,  v.y);
                acc_fp8x4(a + 8,  v.z);
                acc_fp8x4(a + 12, v.w);
            }
            const float inv = 1.0f / fmaxf((float)degi, 1.0f);
            const size_t i = (size_t)node * HID_C + c16 * 16;
            const uint4 tvL = *(const uint4*)(t1b + i);
            const uint4 tvH = *(const uint4*)(t1b + i + 8);
            float r[16];
#pragma unroll
            for (int z = 0; z < 4; ++z) {
                const float4 bv = *(const float4*)(b1 + c16 * 16 + z * 4);
                const uint_t t01 = (z < 2) ? ((z == 0) ? tvL.x : tvL.y)
                                           : ((z == 2) ? tvH.x : tvH.y);
                (void)t01;
                r[z*4+0] = bv.x; r[z*4+1] = bv.y; r[z*4+2] = bv.z; r[z*4+3] = bv.w;
            }
            const uint_t tw[8] = {tvL.x, tvL.y, tvL.z, tvL.w, tvH.x, tvH.y, tvH.z, tvH.w};
#pragma unroll
            for (int z = 0; z < 8; ++z) {
                r[z*2+0] = fmaxf(fmaf(a[z*2+0], inv, r[z*2+0] + bflo(tw[z])), 0.0f);
                r[z*2+1] = fmaxf(fmaf(a[z*2+1], inv, r[z*2+1] + bfhi(tw[z])), 0.0f);
            }
            oL.x = (uint_t)f2bf(r[0])  | ((uint_t)f2bf(r[1])  << 16);
            oL.y = (uint_t)f2bf(r[2])  | ((uint_t)f2bf(r[3])  << 16);
            oL.z = (uint_t)f2bf(r[4])  | ((uint_t)f2bf(r[5])  << 16);
            oL.w = (uint_t)f2bf(r[6])  | ((uint_t)f2bf(r[7])  << 16);
            oH.x = (uint_t)f2bf(r[8])  | ((uint_t)f2bf(r[9])  << 16);
            oH.y = (uint_t)f2bf(r[10]) | ((uint_t)f2bf(r[11]) << 16);
            oH.z = (uint_t)f2bf(r[12]) | ((uint_t)f2bf(r[13]) << 16);
            oH.w = (uint_t)f2bf(r[14]) | ((uint_t)f2bf(r[15]) << 16);
        }
        *(uint4*)&hs[nl * HS_STRIDE + c16 * 16] = oL;
        *(uint4*)&hs[nl * HS_STRIDE + c16 * 16 + 8] = oH;
    }
    __syncthreads();

    // ---- Phase B: MFMA. Wave wv owns rows wv*16..wv*16+15. ----
    const int wv   = tid >> 6;
    const int lane = tid & 63;
    const int quad = lane >> 4;
    const int m    = lane & 15;
    const int row0 = blk * 64 + wv * 16;

    const bf16x8* Bl = (const bf16x8*)(wpack + 32768);
    const bf16x8* Br = (const bf16x8*)(wpack + 40960);

    f32x4 accl[4], accr[4];
#pragma unroll
    for (int ct = 0; ct < 4; ++ct) { accl[ct] = (f32x4)(0.0f); accr[ct] = (f32x4)(0.0f); }

#pragma unroll
    for (int kt = 0; kt < 4; ++kt) {
        const bf16x8 af = *(const bf16x8*)&hs[(wv * 16 + m) * HS_STRIDE + kt * 32 + quad * 8];
#pragma unroll
        for (int ct = 0; ct < 4; ++ct) {
            const bf16x8 bl = Bl[(ct * 4 + kt) * 64 + lane];
            const bf16x8 br = Br[(ct * 4 + kt) * 64 + lane];
            accl[ct] = __builtin_amdgcn_mfma_f32_16x16x32_bf16(af, bl, accl[ct], 0, 0, 0);
            accr[ct] = __builtin_amdgcn_mfma_f32_16x16x32_bf16(af, br, accr[ct], 0, 0, 0);
        }
    }

#pragma unroll
    for (int r = 0; r < 4; ++r) {
        const int orow = row0 + quad * 4 + r;
        if (orow < N_NODES) {
#pragma unroll
            for (int ct = 0; ct < 4; ++ct) {
                const int col = ct * 16 + m;
                p2f[(size_t)orow * OUT_C + col] = f2fp8(accl[ct][r]);
                t2b[(size_t)orow * OUT_C + col] = f2bf(accr[ct][r]);
            }
        }
    }
}

// ---------------------------------------------------------------------------
// agg2: 64 nodes/block, 4 lanes/node, uint4 loads (16 fp8 ch/lane).
// out = mean(p2[src]) + b2 + t2.
// ---------------------------------------------------------------------------
__global__ __launch_bounds__(256) void agg2_kernel(
    const uchar_t* __restrict__ p2f, const ushort_t* __restrict__ t2b,
    const float* __restrict__ b2, const int* __restrict__ row_ptr,
    const int* __restrict__ cnt, const int* __restrict__ csr,
    float* __restrict__ out)
{
    const int c16 = threadIdx.x & 3;           // channels 16*c16 .. 16*c16+15
    const int grp = threadIdx.x >> 2;          // 0..63
    const uint4* p2v = (const uint4*)p2f;      // row stride 4 uint4

    const int node = blockIdx.x * 64 + grp;
    if (node >= N_NODES) return;
    const int start = row_ptr[node];
    const int degi  = cnt[node];
    float a[16];
#pragma unroll
    for (int z = 0; z < 16; ++z) a[z] = 0.0f;
    int e = 0;
    for (; e + 3 < degi; e += 4) {
        const int s0 = csr[start + e];
        const int s1 = csr[start + e + 1];
        const int s2 = csr[start + e + 2];
        const int s3 = csr[start + e + 3];
        const uint4 v0 = p2v[(size_t)s0 * 4 + c16];
        const uint4 v1 = p2v[(size_t)s1 * 4 + c16];
        const uint4 v2 = p2v[(size_t)s2 * 4 + c16];
        const uint4 v3 = p2v[(size_t)s3 * 4 + c16];
#pragma unroll
        for (int q = 0; q < 4; ++q) {
            const uint4 v = (q == 0) ? v0 : (q == 1) ? v1 : (q == 2) ? v2 : v3;
            acc_fp8x4(a + 0,  v.x);
            acc_fp8x4(a + 4,  v.y);
            acc_fp8x4(a + 8,  v.z);
            acc_fp8x4(a + 12, v.w);
        }
    }
    for (; e < degi; ++e) {
        const uint4 v = p2v[(size_t)csr[start + e] * 4 + c16];
        acc_fp8x4(a + 0,  v.x);
        acc_fp8x4(a + 4,  v.y);
        acc_fp8x4(a + 8,  v.z);
        acc_fp8x4(a + 12, v.w);
    }

    const float inv = 1.0f / fmaxf((float)degi, 1.0f);
    const size_t i = (size_t)node * OUT_C + c16 * 16;
    const uint4 tvL = *(const uint4*)(t2b + i);
    const uint4 tvH = *(const uint4*)(t2b + i + 8);
    const uint_t tw[8] = {tvL.x, tvL.y, tvL.z, tvL.w, tvH.x, tvH.y, tvH.z, tvH.w};
#pragma unroll
    for (int z = 0; z < 4; ++z) {
        const float4 bv = *(const float4*)(b2 + c16 * 16 + z * 4);
        float4 o;
        o.x = fmaf(a[z*4+0], inv, bv.x + bflo(tw[z*2+0]));
        o.y = fmaf(a[z*4+1], inv, bv.y + bfhi(tw[z*2+0]));
        o.z = fmaf(a[z*4+2], inv, bv.z + bflo(tw[z*2+1]));
        o.w = fmaf(a[z*4+3], inv, bv.w + bfhi(tw[z*2+1]));
        *(float4*)(out + i + z * 4) = o;
    }
}

extern "C" void kernel_launch(void* const* d_in, const int* in_sizes, int n_in,
                              void* d_out, int out_size, void* d_ws, size_t ws_size,
                              hipStream_t stream)
{
    const float* x   = (const float*)d_in[0];
    const int*   ei  = (const int*)d_in[1];
    const float* W1l = (const float*)d_in[2];
    const float* b1  = (const float*)d_in[3];
    const float* W1r = (const float*)d_in[4];
    const float* W2l = (const float*)d_in[5];
    const float* b2  = (const float*)d_in[6];
    const float* W2r = (const float*)d_in[7];
    float* out = (float*)d_out;

    const int* src = ei;
    const int* dst = ei + N_EDGES;

    const size_t NH = (size_t)N_NODES * HID_C;   // 6.4M
    const size_t NO = (size_t)N_NODES * OUT_C;   // 3.2M
    const size_t EB = (size_t)NBUCK * BCAP;      // 1.204M slots
    const size_t CB = (size_t)L2F_BLKS * QCAP;   // 1.204M csr slots

    // Workspace layout (8B-aligned first, bytes last). p1f/p2f 16B-aligned
    // (offsets are multiples of 16 from the 256B-aligned base).
    char* ws = (char*)d_ws;
    ushort_t* t1b   = (ushort_t*)ws;                   ws += NH * sizeof(ushort_t);
    ushort_t* t2b   = (ushort_t*)ws;                   ws += NO * sizeof(ushort_t);
    ushort_t* wpack = (ushort_t*)ws;                   ws += 49152 * sizeof(ushort_t);
    int* ebuf    = (int*)ws;                           ws += EB * sizeof(int);
    int* csr     = (int*)ws;                           ws += CB * sizeof(int);
    int* cnt     = (int*)ws;                           ws += N_NODES * sizeof(int);
    int* row_ptr = (int*)ws;                           ws += N_NODES * sizeof(int);
    int* gcur    = (int*)ws;                           ws += NBUCK * sizeof(int);
    ws += (16 - ((size_t)(ws - (char*)d_ws) & 15)) & 15;   // align 16
    uchar_t* p1f = (uchar_t*)ws;                       ws += NH * sizeof(uchar_t);
    uchar_t* p2f = (uchar_t*)ws;                       ws += NO * sizeof(uchar_t);

    const size_t need = (size_t)(ws - (char*)d_ws);
    if (ws_size < need) return;

    // K0: pack weights | zero bucket cursors        (input-only)
    k0_kernel<<<PACK_BLKS + 1, 256, 0, stream>>>(W1l, W1r, W2l, W2r, wpack, gcur);
    // K1: mm1 | bucket scatter                      (reads only K0 outputs/inputs)
    k1_kernel<<<MM1_BLKS + EBLKS, 256, 0, stream>>>(
        x, wpack, p1f, t1b, src, dst, gcur, ebuf);
    // Fused fill + agg1 + mm2 (quarter-bucket blocks; csr built in LDS)
    l2f_kernel<<<L2F_BLKS, 256, 0, stream>>>(
        ebuf, gcur, cnt, row_ptr, csr, p1f, t1b, b1, wpack, p2f, t2b);
    // Final aggregation
    agg2_kernel<<<MM1_BLKS, 256, 0, stream>>>(
        p2f, t2b, b2, row_ptr, cnt, csr, out);
}